// Round 1
// baseline (648.911 us; speedup 1.0000x reference)
//
#include <hip/hip_runtime.h>
#include <math.h>

#define N_NODES 100000
#define N_EDGES 1600000
#define F 128

typedef unsigned int u32;

// ---------------- helpers ----------------

__device__ __forceinline__ u32 key_of(float s) {
    u32 u = __float_as_uint(s);
    // monotone map: larger float -> larger key (descending top-k = largest keys)
    return (u & 0x80000000u) ? ~u : (u | 0x80000000u);
}

__device__ __forceinline__ float wave_reduce(float v) {
    #pragma unroll
    for (int off = 32; off > 0; off >>= 1) v += __shfl_down(v, off, 64);
    return v;
}

// ---------------- 1. p / ||p||, init state ----------------

__global__ void k_pnorm(const float* __restrict__ p, float* __restrict__ pscaled,
                        u32* __restrict__ state) {
    __shared__ float sh[F];
    __shared__ float inv;
    int t = threadIdx.x;
    sh[t] = p[t] * p[t];
    __syncthreads();
    if (t == 0) {
        float s = 0.f;
        for (int i = 0; i < F; i++) s += sh[i];
        inv = 1.0f / sqrtf(s);
        state[1] = 128u;   // k_rem; state[0]/[2]/[3] zeroed by memset
    }
    __syncthreads();
    pscaled[t] = p[t] * inv;
}

// ---------------- 2. scores[i] = x[i] . pscaled ----------------

__global__ void k_scores(const float* __restrict__ x, const float* __restrict__ ps,
                         float* __restrict__ scores) {
    int node = blockIdx.x * 4 + (threadIdx.x >> 6);
    int lane = threadIdx.x & 63;
    if (node >= N_NODES) return;
    float2 xv = *(const float2*)&x[(size_t)node * F + lane * 2];
    float2 pv = *(const float2*)&ps[lane * 2];
    float d = xv.x * pv.x + xv.y * pv.y;
    d = wave_reduce(d);
    if (lane == 0) scores[node] = d;
}

// ---------------- 3. radix-select top-128 (exact, jax tie semantics) ----------------

__global__ void k_hist(const float* __restrict__ scores, u32* __restrict__ hist,
                       const u32* __restrict__ state, int pass) {
    __shared__ u32 h[256];
    int t = threadIdx.x;
    h[t] = 0;
    __syncthreads();
    u32 prefix = state[0];
    int shift = 24 - 8 * pass;
    for (int i = blockIdx.x * blockDim.x + t; i < N_NODES; i += gridDim.x * blockDim.x) {
        u32 k = key_of(scores[i]);
        bool keep = (pass == 0) || ((k >> (shift + 8)) == prefix);
        if (keep) atomicAdd(&h[(k >> shift) & 255u], 1u);
    }
    __syncthreads();
    if (h[t]) atomicAdd(&hist[t], h[t]);
}

__global__ void k_scan(u32* __restrict__ hist, u32* __restrict__ state) {
    if (threadIdx.x != 0) return;
    u32 krem = state[1], prefix = state[0];
    u32 cum = 0; int b = 0;
    for (int v = 255; v >= 0; v--) {
        u32 c = hist[v];
        if (cum + c >= krem) { b = v; break; }
        cum += c;
    }
    state[0] = (prefix << 8) | (u32)b;
    state[1] = krem - cum;
    for (int v = 0; v < 256; v++) hist[v] = 0;   // ready for next pass
}

__global__ void k_collect(const float* __restrict__ scores, u32* __restrict__ state,
                          u32* __restrict__ selG, u32* __restrict__ tie) {
    u32 T = state[0];
    for (int i = blockIdx.x * blockDim.x + threadIdx.x; i < N_NODES;
         i += gridDim.x * blockDim.x) {
        u32 k = key_of(scores[i]);
        if (k > T) {
            u32 pos = atomicAdd(&state[2], 1u);
            if (pos < 128) selG[pos] = (u32)i;
        } else if (k == T) {
            u32 pos = atomicAdd(&state[3], 1u);
            if (pos < 2048) tie[pos] = (u32)i;
        }
    }
}

__global__ void k_assemble(const float* __restrict__ scores, const u32* __restrict__ state,
                           const u32* __restrict__ selG, const u32* __restrict__ tie,
                           u32* __restrict__ top_idx, float* __restrict__ gate) {
    __shared__ u32 cand[128];
    __shared__ float cs[128];
    int t = threadIdx.x;                 // 128 threads
    u32 g = state[2]; if (g > 128u) g = 128u;
    u32 nE = state[3]; if (nE > 2048u) nE = 2048u;
    int r = 128 - (int)g;                // needed at exactly-threshold value
    if (t < (int)g) cand[t] = selG[t];
    __syncthreads();
    // ties: pick r smallest indices (jax tie-break: lower index first)
    for (int s = t; s < (int)nE; s += 128) {
        u32 v = tie[s];
        int rank = 0;
        for (int j = 0; j < (int)nE; j++) rank += (tie[j] < v);
        if (rank < r) cand[g + rank] = v;
    }
    __syncthreads();
    u32 my = cand[t];
    float msc = scores[my];
    cs[t] = msc;
    __syncthreads();
    u32 mk = key_of(msc);
    int rank = 0;
    for (int j = 0; j < 128; j++) {
        u32 ok = key_of(cs[j]);
        rank += (int)((ok > mk) || (ok == mk && cand[j] < my));
    }
    top_idx[rank] = my;
    gate[rank] = tanhf(msc);
}

// ---------------- 4. GRU step -> W_new ----------------
// one block per row r; coalesced wave-reductions over w_ih / w_hh rows

__global__ void k_gru(const float* __restrict__ x, const float* __restrict__ W,
                      const float* __restrict__ w_ih, const float* __restrict__ w_hh,
                      const float* __restrict__ b_ih, const float* __restrict__ b_hh,
                      const u32* __restrict__ top_idx, const float* __restrict__ gate,
                      float* __restrict__ Wnew) {
    __shared__ float xt[F], wr[F], g[768];
    int r = blockIdx.x, t = threadIdx.x;
    if (t < F) {
        u32 idx = top_idx[r];
        float gt = gate[r];
        xt[t] = x[(size_t)idx * F + t] * gt;
        wr[t] = W[r * F + t];
    }
    __syncthreads();
    int wave = t >> 6, lane = t & 63;
    for (int idx = wave; idx < 768; idx += 4) {
        const float* mat; const float* src; int j;
        if (idx < 384) { j = idx;       mat = w_ih; src = xt; }
        else           { j = idx - 384; mat = w_hh; src = wr; }
        float2 a = *(const float2*)&mat[j * F + lane * 2];
        float2 b = *(const float2*)&src[lane * 2];
        float d = a.x * b.x + a.y * b.y;
        d = wave_reduce(d);
        if (lane == 0) g[idx] = d;
    }
    __syncthreads();
    if (t < F) {
        int h = t;
        float gir = g[h]         + b_ih[h];
        float giz = g[F + h]     + b_ih[F + h];
        float gin = g[2 * F + h] + b_ih[2 * F + h];
        float ghr = g[384 + h]         + b_hh[h];
        float ghz = g[384 + F + h]     + b_hh[F + h];
        float ghn = g[384 + 2 * F + h] + b_hh[2 * F + h];
        float rg = 1.0f / (1.0f + expf(-(gir + ghr)));
        float z  = 1.0f / (1.0f + expf(-(giz + ghz)));
        float n  = tanhf(gin + rg * ghn);
        Wnew[r * F + h] = (1.0f - z) * n + z * wr[h];
    }
}

// ---------------- 5. degree count / dinv / CSR build ----------------

__global__ void k_count(const int* __restrict__ ei, u32* __restrict__ cnt) {
    for (int e = blockIdx.x * blockDim.x + threadIdx.x; e < N_EDGES;
         e += gridDim.x * blockDim.x)
        atomicAdd(&cnt[ei[N_EDGES + e]], 1u);
}

__global__ void k_dinv(const u32* __restrict__ cnt, float* __restrict__ dinv) {
    int i = blockIdx.x * blockDim.x + threadIdx.x;
    if (i < N_NODES) dinv[i] = 1.0f / sqrtf((float)cnt[i] + 1.0f);
}

#define CHUNK 1024
__global__ void k_scan1(const u32* __restrict__ cnt, u32* __restrict__ offs,
                        u32* __restrict__ part) {
    __shared__ u32 sh[256];
    int t = threadIdx.x;
    int base = blockIdx.x * CHUNK + t * 4;
    u32 v[4];
    #pragma unroll
    for (int j = 0; j < 4; j++) v[j] = (base + j < N_NODES) ? cnt[base + j] : 0u;
    u32 s = v[0] + v[1] + v[2] + v[3];
    sh[t] = s;
    __syncthreads();
    for (int off = 1; off < 256; off <<= 1) {
        u32 val = (t >= off) ? sh[t - off] : 0u;
        __syncthreads();
        sh[t] += val;
        __syncthreads();
    }
    u32 run = sh[t] - s;   // exclusive within chunk
    #pragma unroll
    for (int j = 0; j < 4; j++) {
        if (base + j < N_NODES) offs[base + j] = run;
        run += v[j];
    }
    if (t == 255) part[blockIdx.x] = sh[255];
}

__global__ void k_scan2(u32* __restrict__ part, int n) {
    if (threadIdx.x != 0) return;
    u32 run = 0;
    for (int b = 0; b < n; b++) { u32 v = part[b]; part[b] = run; run += v; }
}

__global__ void k_scan3(u32* __restrict__ offs, const u32* __restrict__ part) {
    int i = blockIdx.x * blockDim.x + threadIdx.x;
    if (i < N_NODES) offs[i] += part[i >> 10];
    if (i == 0) offs[N_NODES] = N_EDGES;
}

__global__ void k_bin(const int* __restrict__ ei, const u32* __restrict__ offs,
                      u32* __restrict__ curs, u32* __restrict__ ebuf) {
    for (int e = blockIdx.x * blockDim.x + threadIdx.x; e < N_EDGES;
         e += gridDim.x * blockDim.x) {
        int c = ei[N_EDGES + e];
        u32 pos = offs[c] + atomicAdd(&curs[c], 1u);
        ebuf[pos] = (u32)ei[e];
    }
}

// ---------------- 6. xw = x @ W_new  (fp32 vector GEMM, 48x64 tiles) ----------------

__global__ __launch_bounds__(256) void k_gemm(const float* __restrict__ x,
                                              const float* __restrict__ Wn,
                                              float* __restrict__ xw) {
    __shared__ float xS[48][129];   // +1 pad: staging writes spread banks
    __shared__ float Wt[128][64];
    int t = threadIdx.x;
    int r0 = blockIdx.x * 48;
    int c0 = blockIdx.y * 64;
    // stage x tile (48 x 128)
    #pragma unroll
    for (int i = 0; i < 6; i++) {
        int l = t + i * 256;
        int row = l >> 5, c4 = l & 31;
        float4 v = {0.f, 0.f, 0.f, 0.f};
        if (r0 + row < N_NODES) v = *(const float4*)&x[(size_t)(r0 + row) * F + c4 * 4];
        xS[row][c4 * 4 + 0] = v.x; xS[row][c4 * 4 + 1] = v.y;
        xS[row][c4 * 4 + 2] = v.z; xS[row][c4 * 4 + 3] = v.w;
    }
    // stage W tile (128 x 64)
    #pragma unroll
    for (int i = 0; i < 8; i++) {
        int l = t + i * 256;
        int f = l >> 4, c4 = l & 15;
        float4 v = *(const float4*)&Wn[f * F + c0 + c4 * 4];
        *(float4*)&Wt[f][c4 * 4] = v;
    }
    __syncthreads();
    int ty = t >> 4, tx = t & 15;   // 16x16 threads; 3 rows x 4 cols each
    float acc[3][4] = {};
    #pragma unroll 4
    for (int f = 0; f < F; f++) {
        float4 b = *(const float4*)&Wt[f][tx * 4];
        float a0 = xS[ty * 3 + 0][f];
        float a1 = xS[ty * 3 + 1][f];
        float a2 = xS[ty * 3 + 2][f];
        acc[0][0] += a0 * b.x; acc[0][1] += a0 * b.y; acc[0][2] += a0 * b.z; acc[0][3] += a0 * b.w;
        acc[1][0] += a1 * b.x; acc[1][1] += a1 * b.y; acc[1][2] += a1 * b.z; acc[1][3] += a1 * b.w;
        acc[2][0] += a2 * b.x; acc[2][1] += a2 * b.y; acc[2][2] += a2 * b.z; acc[2][3] += a2 * b.w;
    }
    #pragma unroll
    for (int k = 0; k < 3; k++) {
        int row = r0 + ty * 3 + k;
        if (row < N_NODES) {
            float4 v = {acc[k][0], acc[k][1], acc[k][2], acc[k][3]};
            *(float4*)&xw[(size_t)row * F + c0 + tx * 4] = v;
        }
    }
}

// ---------------- 7. gather-aggregate + fused head ----------------
// one wave per destination node; epilogue fuses self-loop, bias, ReLU, lin

__global__ void k_gather(const float* __restrict__ xw, const u32* __restrict__ offs,
                         const u32* __restrict__ ebuf, const float* __restrict__ dinv,
                         const float* __restrict__ conv_bias, const float* __restrict__ lin_w,
                         const float* __restrict__ lin_b, float* __restrict__ out) {
    int c = blockIdx.x * 4 + (threadIdx.x >> 6);
    if (c >= N_NODES) return;
    int lane = threadIdx.x & 63;
    u32 jbeg = offs[c], jend = offs[c + 1];
    float2 acc = {0.f, 0.f};
    if (jbeg < jend) {
        u32 ridx = ebuf[jbeg];
        for (u32 j = jbeg; j < jend; j++) {
            u32 nridx = (j + 1 < jend) ? ebuf[j + 1] : 0u;   // light prefetch
            float w = dinv[ridx];
            float2 v = *(const float2*)&xw[(size_t)ridx * F + lane * 2];
            acc.x += w * v.x;
            acc.y += w * v.y;
            ridx = nridx;
        }
    }
    float dc = dinv[c];
    float2 sv = *(const float2*)&xw[(size_t)c * F + lane * 2];
    acc.x = dc * acc.x + dc * dc * sv.x + conv_bias[lane * 2];
    acc.y = dc * acc.y + dc * dc * sv.y + conv_bias[lane * 2 + 1];
    float hx = fmaxf(acc.x, 0.f), hy = fmaxf(acc.y, 0.f);
    float part = hx * lin_w[lane * 2] + hy * lin_w[lane * 2 + 1];
    part = wave_reduce(part);
    if (lane == 0) out[c] = part + lin_b[0];
}

// ---------------- launch ----------------

extern "C" void kernel_launch(void* const* d_in, const int* in_sizes, int n_in,
                              void* d_out, int out_size, void* d_ws, size_t ws_size,
                              hipStream_t stream) {
    const float* x         = (const float*)d_in[0];
    const int*   ei        = (const int*)  d_in[1];
    const float* W         = (const float*)d_in[2];
    const float* p         = (const float*)d_in[3];
    const float* w_ih      = (const float*)d_in[4];
    const float* w_hh      = (const float*)d_in[5];
    const float* b_ih      = (const float*)d_in[6];
    const float* b_hh      = (const float*)d_in[7];
    const float* conv_bias = (const float*)d_in[8];
    const float* lin_w     = (const float*)d_in[9];
    const float* lin_b     = (const float*)d_in[10];
    float* out = (float*)d_out;

    u32*   w  = (u32*)d_ws;
    float* wf = (float*)d_ws;

    // ws layout (word offsets). total ~59.7 MB
    const size_t SCORES_W = 0;
    const size_t DINV_W   = 100096;
    const size_t CNT_W    = 200192;
    const size_t OFFS_W   = 300288;   // 100001 words
    const size_t CURS_W   = 400416;
    const size_t PART_W   = 500416;   // 128 words
    const size_t META_W   = 500544;   // hist[256], state[4], selG[128], tie[2048], topidx[128], gate[128], pscaled[128]
    const size_t WNEW_W   = 503424;
    const size_t EBUF_W   = 519808;
    const size_t XW_W     = 2119808;

    float* scores  = wf + SCORES_W;
    float* dinv    = wf + DINV_W;
    u32*   cnt     = w  + CNT_W;
    u32*   offs    = w  + OFFS_W;
    u32*   curs    = w  + CURS_W;
    u32*   part    = w  + PART_W;
    u32*   hist    = w  + META_W;
    u32*   state   = w  + META_W + 256;
    u32*   selG    = w  + META_W + 260;
    u32*   tie     = w  + META_W + 388;
    u32*   top_idx = w  + META_W + 2436;
    float* gate    = wf + META_W + 2564;
    float* pscaled = wf + META_W + 2692;
    float* Wnew    = wf + WNEW_W;
    u32*   ebuf    = w  + EBUF_W;
    float* xw      = wf + XW_W;

    hipMemsetAsync(cnt,  0, N_NODES * sizeof(u32), stream);
    hipMemsetAsync(curs, 0, N_NODES * sizeof(u32), stream);
    hipMemsetAsync(hist, 0, 260 * sizeof(u32), stream);   // hist + state

    k_pnorm<<<1, 128, 0, stream>>>(p, pscaled, state);
    k_scores<<<25000, 256, 0, stream>>>(x, pscaled, scores);
    for (int pass = 0; pass < 4; pass++) {
        k_hist<<<256, 256, 0, stream>>>(scores, hist, state, pass);
        k_scan<<<1, 64, 0, stream>>>(hist, state);
    }
    k_collect<<<256, 256, 0, stream>>>(scores, state, selG, tie);
    k_assemble<<<1, 128, 0, stream>>>(scores, state, selG, tie, top_idx, gate);
    k_gru<<<128, 256, 0, stream>>>(x, W, w_ih, w_hh, b_ih, b_hh, top_idx, gate, Wnew);

    k_count<<<1024, 256, 0, stream>>>(ei, cnt);
    k_dinv<<<(N_NODES + 255) / 256, 256, 0, stream>>>(cnt, dinv);
    k_scan1<<<98, 256, 0, stream>>>(cnt, offs, part);
    k_scan2<<<1, 64, 0, stream>>>(part, 98);
    k_scan3<<<(N_NODES + 255) / 256, 256, 0, stream>>>(offs, part);
    k_bin<<<1024, 256, 0, stream>>>(ei, offs, curs, ebuf);

    dim3 ggrid(2084, 2, 1);   // ceil(100000/48) x (128/64)
    k_gemm<<<ggrid, 256, 0, stream>>>(x, Wnew, xw);

    k_gather<<<25000, 256, 0, stream>>>(xw, offs, ebuf, dinv, conv_bias, lin_w,
                                        lin_b, out);
}

// Round 3
// 622.313 us; speedup vs baseline: 1.0427x; 1.0427x over previous
//
#include <hip/hip_runtime.h>
#include <math.h>

#define N_NODES 100000
#define N_EDGES 1600000
#define F 128

typedef unsigned int u32;
typedef unsigned short u16;

// ---------------- helpers ----------------

__device__ __forceinline__ u32 key_of(float s) {
    u32 u = __float_as_uint(s);
    // monotone map: larger float -> larger u32 key
    return (u & 0x80000000u) ? ~u : (u | 0x80000000u);
}

__device__ __forceinline__ float wave_reduce(float v) {
    #pragma unroll
    for (int off = 32; off > 0; off >>= 1) v += __shfl_down(v, off, 64);
    return v;
}

__device__ __forceinline__ u16 f2bf(float f) {   // round-to-nearest-even
    u32 u = __float_as_uint(f);
    u += 0x7fffu + ((u >> 16) & 1u);
    return (u16)(u >> 16);
}

// ---------------- 1. p / ||p||, init state ----------------

__global__ void k_pnorm(const float* __restrict__ p, float* __restrict__ pscaled,
                        u32* __restrict__ state) {
    __shared__ float sh[F];
    __shared__ float inv;
    int t = threadIdx.x;
    sh[t] = p[t] * p[t];
    __syncthreads();
    if (t == 0) {
        float s = 0.f;
        for (int i = 0; i < F; i++) s += sh[i];
        inv = 1.0f / sqrtf(s);
        state[1] = 128u;   // k_rem; state[0]/[2]/[3] zeroed by memset
    }
    __syncthreads();
    pscaled[t] = p[t] * inv;
}

// ---------------- 2. scores[i] = x[i] . pscaled ----------------

__global__ void k_scores(const float* __restrict__ x, const float* __restrict__ ps,
                         float* __restrict__ scores) {
    int node = blockIdx.x * 4 + (threadIdx.x >> 6);
    int lane = threadIdx.x & 63;
    if (node >= N_NODES) return;
    float2 xv = *(const float2*)&x[(size_t)node * F + lane * 2];
    float2 pv = *(const float2*)&ps[lane * 2];
    float d = xv.x * pv.x + xv.y * pv.y;
    d = wave_reduce(d);
    if (lane == 0) scores[node] = d;
}

// ---------------- 3. radix-select top-128 (exact, jax tie semantics) ----------------

__global__ void k_hist(const float* __restrict__ scores, u32* __restrict__ hist,
                       const u32* __restrict__ state, int pass) {
    __shared__ u32 h[256];
    int t = threadIdx.x;
    h[t] = 0;
    __syncthreads();
    u32 prefix = state[0];
    int shift = 24 - 8 * pass;
    for (int i = blockIdx.x * blockDim.x + t; i < N_NODES; i += gridDim.x * blockDim.x) {
        u32 k = key_of(scores[i]);
        bool keep = (pass == 0) || ((k >> (shift + 8)) == prefix);
        if (keep) atomicAdd(&h[(k >> shift) & 255u], 1u);
    }
    __syncthreads();
    if (h[t]) atomicAdd(&hist[t], h[t]);
}

__global__ void k_scan(u32* __restrict__ hist, u32* __restrict__ state) {
    if (threadIdx.x != 0) return;
    u32 krem = state[1], prefix = state[0];
    u32 cum = 0; int b = 0;
    for (int v = 255; v >= 0; v--) {
        u32 c = hist[v];
        if (cum + c >= krem) { b = v; break; }
        cum += c;
    }
    state[0] = (prefix << 8) | (u32)b;
    state[1] = krem - cum;
    for (int v = 0; v < 256; v++) hist[v] = 0;   // ready for next pass
}

__global__ void k_collect(const float* __restrict__ scores, u32* __restrict__ state,
                          u32* __restrict__ selG, u32* __restrict__ tie) {
    u32 T = state[0];
    for (int i = blockIdx.x * blockDim.x + threadIdx.x; i < N_NODES;
         i += gridDim.x * blockDim.x) {
        u32 k = key_of(scores[i]);
        if (k > T) {
            u32 pos = atomicAdd(&state[2], 1u);
            if (pos < 128) selG[pos] = (u32)i;
        } else if (k == T) {
            u32 pos = atomicAdd(&state[3], 1u);
            if (pos < 2048) tie[pos] = (u32)i;
        }
    }
}

__global__ void k_assemble(const float* __restrict__ scores, const u32* __restrict__ state,
                           const u32* __restrict__ selG, const u32* __restrict__ tie,
                           u32* __restrict__ top_idx, float* __restrict__ gate) {
    __shared__ u32 cand[128];
    __shared__ float cs[128];
    int t = threadIdx.x;                 // 128 threads
    u32 g = state[2]; if (g > 128u) g = 128u;
    u32 nE = state[3]; if (nE > 2048u) nE = 2048u;
    int r = 128 - (int)g;                // needed at exactly-threshold value
    if (t < (int)g) cand[t] = selG[t];
    __syncthreads();
    // ties: pick r smallest indices (jax tie-break: lower index first)
    for (int s = t; s < (int)nE; s += 128) {
        u32 v = tie[s];
        int rank = 0;
        for (int j = 0; j < (int)nE; j++) rank += (tie[j] < v);
        if (rank < r) cand[g + rank] = v;
    }
    __syncthreads();
    u32 my = cand[t];
    float msc = scores[my];
    cs[t] = msc;
    __syncthreads();
    u32 mk = key_of(msc);
    int rank = 0;
    for (int j = 0; j < 128; j++) {
        u32 ok = key_of(cs[j]);
        rank += (int)((ok > mk) || (ok == mk && cand[j] < my));
    }
    top_idx[rank] = my;
    gate[rank] = tanhf(msc);
}

// ---------------- 4. GRU step -> W_new ----------------

__global__ void k_gru(const float* __restrict__ x, const float* __restrict__ W,
                      const float* __restrict__ w_ih, const float* __restrict__ w_hh,
                      const float* __restrict__ b_ih, const float* __restrict__ b_hh,
                      const u32* __restrict__ top_idx, const float* __restrict__ gate,
                      float* __restrict__ Wnew) {
    __shared__ float xt[F], wr[F], g[768];
    int r = blockIdx.x, t = threadIdx.x;
    if (t < F) {
        u32 idx = top_idx[r];
        float gt = gate[r];
        xt[t] = x[(size_t)idx * F + t] * gt;
        wr[t] = W[r * F + t];
    }
    __syncthreads();
    int wave = t >> 6, lane = t & 63;
    for (int idx = wave; idx < 768; idx += 4) {
        const float* mat; const float* src; int j;
        if (idx < 384) { j = idx;       mat = w_ih; src = xt; }
        else           { j = idx - 384; mat = w_hh; src = wr; }
        float2 a = *(const float2*)&mat[j * F + lane * 2];
        float2 b = *(const float2*)&src[lane * 2];
        float d = a.x * b.x + a.y * b.y;
        d = wave_reduce(d);
        if (lane == 0) g[idx] = d;
    }
    __syncthreads();
    if (t < F) {
        int h = t;
        float gir = g[h]         + b_ih[h];
        float giz = g[F + h]     + b_ih[F + h];
        float gin = g[2 * F + h] + b_ih[2 * F + h];
        float ghr = g[384 + h]         + b_hh[h];
        float ghz = g[384 + F + h]     + b_hh[F + h];
        float ghn = g[384 + 2 * F + h] + b_hh[2 * F + h];
        float rg = 1.0f / (1.0f + expf(-(gir + ghr)));
        float z  = 1.0f / (1.0f + expf(-(giz + ghz)));
        float n  = tanhf(gin + rg * ghn);
        Wnew[r * F + h] = (1.0f - z) * n + z * wr[h];
    }
}

// ---------------- 5. degree count / CSR build (dinv fused into scan1) ----------------

__global__ void k_count(const int* __restrict__ ei, u32* __restrict__ cnt) {
    for (int e = blockIdx.x * blockDim.x + threadIdx.x; e < N_EDGES;
         e += gridDim.x * blockDim.x)
        atomicAdd(&cnt[ei[N_EDGES + e]], 1u);
}

#define CHUNK 1024
__global__ void k_scan1(const u32* __restrict__ cnt, u32* __restrict__ offs,
                        u32* __restrict__ part, float* __restrict__ dinv) {
    __shared__ u32 sh[256];
    int t = threadIdx.x;
    int base = blockIdx.x * CHUNK + t * 4;
    u32 v[4];
    #pragma unroll
    for (int j = 0; j < 4; j++) v[j] = (base + j < N_NODES) ? cnt[base + j] : 0u;
    #pragma unroll
    for (int j = 0; j < 4; j++)
        if (base + j < N_NODES) dinv[base + j] = rsqrtf((float)v[j] + 1.0f);
    u32 s = v[0] + v[1] + v[2] + v[3];
    sh[t] = s;
    __syncthreads();
    for (int off = 1; off < 256; off <<= 1) {
        u32 val = (t >= off) ? sh[t - off] : 0u;
        __syncthreads();
        sh[t] += val;
        __syncthreads();
    }
    u32 run = sh[t] - s;   // exclusive within chunk
    #pragma unroll
    for (int j = 0; j < 4; j++) {
        if (base + j < N_NODES) offs[base + j] = run;
        run += v[j];
    }
    if (t == 255) part[blockIdx.x] = sh[255];
}

__global__ void k_scan2(u32* __restrict__ part, int n) {
    if (threadIdx.x != 0) return;
    u32 run = 0;
    for (int b = 0; b < n; b++) { u32 v = part[b]; part[b] = run; run += v; }
}

__global__ void k_scan3(u32* __restrict__ offs, const u32* __restrict__ part) {
    int i = blockIdx.x * blockDim.x + threadIdx.x;
    if (i < N_NODES) offs[i] += part[i >> 10];
    if (i == 0) offs[N_NODES] = N_EDGES;
}

__global__ void k_bin(const int* __restrict__ ei, const u32* __restrict__ offs,
                      u32* __restrict__ curs, u32* __restrict__ ebuf) {
    for (int e = blockIdx.x * blockDim.x + threadIdx.x; e < N_EDGES;
         e += gridDim.x * blockDim.x) {
        int c = ei[N_EDGES + e];
        u32 pos = offs[c] + atomicAdd(&curs[c], 1u);
        ebuf[pos] = (u32)ei[e];
    }
}

// ---------------- 6. xw = x @ W_new  (fp32 vector GEMM, bf16 output) ----------------

__global__ __launch_bounds__(256) void k_gemm(const float* __restrict__ x,
                                              const float* __restrict__ Wn,
                                              u16* __restrict__ xwh) {
    __shared__ float xS[48][129];
    __shared__ float Wt[128][64];
    int t = threadIdx.x;
    int r0 = blockIdx.x * 48;
    int c0 = blockIdx.y * 64;
    #pragma unroll
    for (int i = 0; i < 6; i++) {
        int l = t + i * 256;
        int row = l >> 5, c4 = l & 31;
        float4 v = {0.f, 0.f, 0.f, 0.f};
        if (r0 + row < N_NODES) v = *(const float4*)&x[(size_t)(r0 + row) * F + c4 * 4];
        xS[row][c4 * 4 + 0] = v.x; xS[row][c4 * 4 + 1] = v.y;
        xS[row][c4 * 4 + 2] = v.z; xS[row][c4 * 4 + 3] = v.w;
    }
    #pragma unroll
    for (int i = 0; i < 8; i++) {
        int l = t + i * 256;
        int f = l >> 4, c4 = l & 15;
        float4 v = *(const float4*)&Wn[f * F + c0 + c4 * 4];
        *(float4*)&Wt[f][c4 * 4] = v;
    }
    __syncthreads();
    int ty = t >> 4, tx = t & 15;
    float acc[3][4] = {};
    #pragma unroll 4
    for (int f = 0; f < F; f++) {
        float4 b = *(const float4*)&Wt[f][tx * 4];
        float a0 = xS[ty * 3 + 0][f];
        float a1 = xS[ty * 3 + 1][f];
        float a2 = xS[ty * 3 + 2][f];
        acc[0][0] += a0 * b.x; acc[0][1] += a0 * b.y; acc[0][2] += a0 * b.z; acc[0][3] += a0 * b.w;
        acc[1][0] += a1 * b.x; acc[1][1] += a1 * b.y; acc[1][2] += a1 * b.z; acc[1][3] += a1 * b.w;
        acc[2][0] += a2 * b.x; acc[2][1] += a2 * b.y; acc[2][2] += a2 * b.z; acc[2][3] += a2 * b.w;
    }
    #pragma unroll
    for (int k = 0; k < 3; k++) {
        int row = r0 + ty * 3 + k;
        if (row < N_NODES) {
            ushort4 s;
            s.x = f2bf(acc[k][0]); s.y = f2bf(acc[k][1]);
            s.z = f2bf(acc[k][2]); s.w = f2bf(acc[k][3]);
            *(ushort4*)&xwh[(size_t)row * F + c0 + tx * 4] = s;
        }
    }
}

// ---------------- 7. gather-aggregate + fused head (bf16 xw) ----------------

__global__ void k_gather(const u32* __restrict__ xw32, const u32* __restrict__ offs,
                         const u32* __restrict__ ebuf, const float* __restrict__ dinv,
                         const float* __restrict__ conv_bias, const float* __restrict__ lin_w,
                         const float* __restrict__ lin_b, float* __restrict__ out) {
    int c = blockIdx.x * 4 + (threadIdx.x >> 6);
    if (c >= N_NODES) return;
    int lane = threadIdx.x & 63;
    u32 jbeg = offs[c], jend = offs[c + 1];
    float accx = 0.f, accy = 0.f;
    if (jbeg < jend) {
        u32 ridx = ebuf[jbeg];
        for (u32 j = jbeg; j < jend; j++) {
            u32 nridx = (j + 1 < jend) ? ebuf[j + 1] : 0u;
            float w = dinv[ridx];
            u32 bits = xw32[(size_t)ridx * 64 + lane];   // 2 bf16
            float lo = __uint_as_float(bits << 16);
            float hi = __uint_as_float(bits & 0xffff0000u);
            accx += w * lo;
            accy += w * hi;
            ridx = nridx;
        }
    }
    float dc = dinv[c];
    u32 sbits = xw32[(size_t)c * 64 + lane];
    float slo = __uint_as_float(sbits << 16);
    float shi = __uint_as_float(sbits & 0xffff0000u);
    accx = dc * accx + dc * dc * slo + conv_bias[lane * 2];
    accy = dc * accy + dc * dc * shi + conv_bias[lane * 2 + 1];
    float hx = fmaxf(accx, 0.f), hy = fmaxf(accy, 0.f);
    float part = hx * lin_w[lane * 2] + hy * lin_w[lane * 2 + 1];
    part = wave_reduce(part);
    if (lane == 0) out[c] = part + lin_b[0];
}

// ---------------- launch ----------------

extern "C" void kernel_launch(void* const* d_in, const int* in_sizes, int n_in,
                              void* d_out, int out_size, void* d_ws, size_t ws_size,
                              hipStream_t stream) {
    const float* x         = (const float*)d_in[0];
    const int*   ei        = (const int*)  d_in[1];
    const float* W         = (const float*)d_in[2];
    const float* p         = (const float*)d_in[3];
    const float* w_ih      = (const float*)d_in[4];
    const float* w_hh      = (const float*)d_in[5];
    const float* b_ih      = (const float*)d_in[6];
    const float* b_hh      = (const float*)d_in[7];
    const float* conv_bias = (const float*)d_in[8];
    const float* lin_w     = (const float*)d_in[9];
    const float* lin_b     = (const float*)d_in[10];
    float* out = (float*)d_out;

    u32*   w  = (u32*)d_ws;
    float* wf = (float*)d_ws;

    // ws layout (word offsets), ~34.1 MB total
    const size_t SCORES_W = 0;         // 100000
    const size_t PSC_W    = 100096;    // 128
    const size_t DINV_W   = 100352;    // 100000
    const size_t CNT_W    = 200448;    // 100000
    const size_t OFFS_W   = 300544;    // 100001
    const size_t CURS_W   = 400640;    // 100000
    const size_t PART_W   = 500736;    // 128
    const size_t HIST_W   = 500864;    // 256 (+ state[4] right after)
    const size_t STATE_W  = 501120;    // 4
    const size_t SELG_W   = 501124;    // 128
    const size_t TIE_W    = 501252;    // 2048
    const size_t TOPI_W   = 503300;    // 128
    const size_t GATE_W   = 503428;    // 128
    const size_t WNEW_W   = 503556;    // 16384
    const size_t EBUF_W   = 519940;    // 1600000
    const size_t XWH_W    = 2119940;   // bf16 xw: 6400000 words

    float* scores  = wf + SCORES_W;
    float* pscaled = wf + PSC_W;
    float* dinv    = wf + DINV_W;
    u32*   cnt     = w  + CNT_W;
    u32*   offs    = w  + OFFS_W;
    u32*   curs    = w  + CURS_W;
    u32*   part    = w  + PART_W;
    u32*   hist    = w  + HIST_W;
    u32*   state   = w  + STATE_W;
    u32*   selG    = w  + SELG_W;
    u32*   tie     = w  + TIE_W;
    u32*   top_idx = w  + TOPI_W;
    float* gate    = wf + GATE_W;
    float* Wnew    = wf + WNEW_W;
    u32*   ebuf    = w  + EBUF_W;
    u16*   xwh     = (u16*)(w + XWH_W);
    u32*   xw32    = w + XWH_W;

    hipMemsetAsync(cnt,  0, N_NODES * sizeof(u32), stream);
    hipMemsetAsync(curs, 0, N_NODES * sizeof(u32), stream);
    hipMemsetAsync(hist, 0, 260 * sizeof(u32), stream);   // hist[256] + state[4]

    k_pnorm<<<1, 128, 0, stream>>>(p, pscaled, state);
    k_scores<<<25000, 256, 0, stream>>>(x, pscaled, scores);
    for (int pass = 0; pass < 4; pass++) {
        k_hist<<<256, 256, 0, stream>>>(scores, hist, state, pass);
        k_scan<<<1, 64, 0, stream>>>(hist, state);
    }
    k_collect<<<256, 256, 0, stream>>>(scores, state, selG, tie);
    k_assemble<<<1, 128, 0, stream>>>(scores, state, selG, tie, top_idx, gate);
    k_gru<<<128, 256, 0, stream>>>(x, W, w_ih, w_hh, b_ih, b_hh, top_idx, gate, Wnew);

    k_count<<<1024, 256, 0, stream>>>(ei, cnt);
    k_scan1<<<98, 256, 0, stream>>>(cnt, offs, part, dinv);
    k_scan2<<<1, 64, 0, stream>>>(part, 98);
    k_scan3<<<(N_NODES + 255) / 256, 256, 0, stream>>>(offs, part);
    k_bin<<<1024, 256, 0, stream>>>(ei, offs, curs, ebuf);

    dim3 ggrid(2084, 2, 1);
    k_gemm<<<ggrid, 256, 0, stream>>>(x, Wnew, xwh);

    k_gather<<<25000, 256, 0, stream>>>(xw32, offs, ebuf, dinv, conv_bias, lin_w,
                                        lin_b, out);
}

// Round 4
// 553.505 us; speedup vs baseline: 1.1724x; 1.1243x over previous
//
#include <hip/hip_runtime.h>
#include <math.h>

#define N_NODES 100000
#define N_EDGES 1600000
#define F 128

typedef unsigned int u32;
typedef unsigned short u16;
typedef __attribute__((ext_vector_type(8))) short short8;
typedef __attribute__((ext_vector_type(4))) float floatx4;

// ---------------- helpers ----------------

__device__ __forceinline__ u32 key_of(float s) {
    u32 u = __float_as_uint(s);
    return (u & 0x80000000u) ? ~u : (u | 0x80000000u);   // larger float -> larger key
}

__device__ __forceinline__ float wave_reduce(float v) {
    #pragma unroll
    for (int off = 32; off > 0; off >>= 1) v += __shfl_down(v, off, 64);
    return v;
}

__device__ __forceinline__ u16 f2bf(float f) {   // round-to-nearest-even
    u32 u = __float_as_uint(f);
    u += 0x7fffu + ((u >> 16) & 1u);
    return (u16)(u >> 16);
}

// ---------------- 1. scores[i] = x[i] . p  (selection is scale-invariant) ----------

__global__ void k_scores(const float* __restrict__ x, const float* __restrict__ p,
                         float* __restrict__ scores) {
    int node = blockIdx.x * 4 + (threadIdx.x >> 6);
    int lane = threadIdx.x & 63;
    if (node >= N_NODES) return;
    float2 xv = *(const float2*)&x[(size_t)node * F + lane * 2];
    float2 pv = *(const float2*)&p[lane * 2];
    float d = xv.x * pv.x + xv.y * pv.y;
    d = wave_reduce(d);
    if (lane == 0) scores[node] = d;
}

// ---------------- 2. top-128: one 16-bit histogram pass + exact candidate sort ------

__global__ void k_hist16(const float* __restrict__ scores, u32* __restrict__ hist16) {
    int i = blockIdx.x * blockDim.x + threadIdx.x;
    if (i < N_NODES) atomicAdd(&hist16[key_of(scores[i]) >> 16], 1u);
}

__global__ __launch_bounds__(1024) void k_scan16(const u32* __restrict__ hist16,
                                                 u32* __restrict__ state) {
    __shared__ u32 a[1024];
    int t = threadIdx.x;
    // thread t sums bins [t*64, t*64+64)
    const uint4* h4 = (const uint4*)hist16;
    u32 local = 0;
    #pragma unroll
    for (int i = 0; i < 16; i++) {
        uint4 v = h4[t * 16 + i];
        local += v.x + v.y + v.z + v.w;
    }
    a[t] = local;
    __syncthreads();
    // inclusive suffix scan over 1024 partials
    for (int off = 1; off < 1024; off <<= 1) {
        u32 add = (t + off < 1024) ? a[t + off] : 0u;
        __syncthreads();
        a[t] += add;
        __syncthreads();
    }
    u32 S_above = (t == 1023) ? 0u : a[t + 1];
    if (S_above < 128u && a[t] >= 128u) {     // threshold bucket is in my chunk
        u32 cum = S_above;
        for (int v = t * 64 + 63; v >= t * 64; v--) {
            cum += hist16[v];
            if (cum >= 128u) { state[0] = (u32)v; break; }
        }
    }
}

__global__ void k_collect16(const float* __restrict__ scores, u32* __restrict__ state,
                            u32* __restrict__ cand) {
    u32 T = state[0] << 16;   // keep keys >= T (count >= 128 by construction)
    int i = blockIdx.x * blockDim.x + threadIdx.x;
    if (i < N_NODES) {
        if (key_of(scores[i]) >= T) {
            u32 pos = atomicAdd(&state[2], 1u);
            if (pos < 2048u) cand[pos] = (u32)i;
        }
    }
}

__global__ void k_assemble16(const float* __restrict__ scores, const float* __restrict__ p,
                             const u32* __restrict__ state, const u32* __restrict__ cand,
                             u32* __restrict__ top_idx, float* __restrict__ gate) {
    __shared__ u32 ci[2048];
    __shared__ float csc[2048];
    __shared__ float s_inv;
    int t = threadIdx.x;   // 256 threads
    if (t < 64) {
        float2 pv = *(const float2*)&p[t * 2];
        float d = pv.x * pv.x + pv.y * pv.y;
        d = wave_reduce(d);
        if (t == 0) s_inv = rsqrtf(d);
    }
    u32 nc = state[2]; if (nc > 2048u) nc = 2048u;
    for (u32 i = t; i < nc; i += 256) { u32 ix = cand[i]; ci[i] = ix; csc[i] = scores[ix]; }
    __syncthreads();
    for (u32 i = t; i < nc; i += 256) {
        u32 myk = key_of(csc[i]);
        u32 myi = ci[i];
        int rank = 0;
        for (u32 j = 0; j < nc; j++) {
            u32 ok = key_of(csc[j]);
            rank += (int)((ok > myk) || (ok == myk && ci[j] < myi));
        }
        if (rank < 128) {   // exact jax semantics: value desc, index asc on ties
            top_idx[rank] = myi;
            gate[rank] = tanhf(csc[i] * s_inv);
        }
    }
}

// ---------------- 3. GRU step -> W_new (+ fragment-ordered bf16 B for MFMA) --------

__global__ void k_gru(const float* __restrict__ x, const float* __restrict__ W,
                      const float* __restrict__ w_ih, const float* __restrict__ w_hh,
                      const float* __restrict__ b_ih, const float* __restrict__ b_hh,
                      const u32* __restrict__ top_idx, const float* __restrict__ gate,
                      float* __restrict__ Wnew, u16* __restrict__ Bfrag) {
    __shared__ float xt[F], wr[F], g[768];
    int r = blockIdx.x, t = threadIdx.x;   // r = k-dim row of W
    if (t < F) {
        u32 idx = top_idx[r];
        float gt = gate[r];
        xt[t] = x[(size_t)idx * F + t] * gt;
        wr[t] = W[r * F + t];
    }
    __syncthreads();
    int wave = t >> 6, lane = t & 63;
    for (int idx = wave; idx < 768; idx += 4) {
        const float* mat; const float* src; int j;
        if (idx < 384) { j = idx;       mat = w_ih; src = xt; }
        else           { j = idx - 384; mat = w_hh; src = wr; }
        float2 a = *(const float2*)&mat[j * F + lane * 2];
        float2 b = *(const float2*)&src[lane * 2];
        float d = a.x * b.x + a.y * b.y;
        d = wave_reduce(d);
        if (lane == 0) g[idx] = d;
    }
    __syncthreads();
    if (t < F) {
        int h = t;   // n-dim col of W
        float gir = g[h]         + b_ih[h];
        float giz = g[F + h]     + b_ih[F + h];
        float gin = g[2 * F + h] + b_ih[2 * F + h];
        float ghr = g[384 + h]         + b_hh[h];
        float ghz = g[384 + F + h]     + b_hh[F + h];
        float ghn = g[384 + 2 * F + h] + b_hh[2 * F + h];
        float rg = 1.0f / (1.0f + expf(-(gir + ghr)));
        float z  = 1.0f / (1.0f + expf(-(giz + ghz)));
        float n  = tanhf(gin + rg * ghn);
        float val = (1.0f - z) * n + z * wr[h];
        Wnew[r * F + h] = val;
        // fragment-ordered bf16 B: B[k=r][n=h] -> frag (nb,kc,lane=q*16+m,j)
        int nb = h >> 4, kc = r >> 5, q = (r >> 3) & 3, m = h & 15, jj = r & 7;
        Bfrag[(((nb * 4 + kc) * 64) + q * 16 + m) * 8 + jj] = f2bf(val);
    }
}

// ---------------- 4. degree count / CSR build ----------------

__global__ void k_count(const int* __restrict__ ei, u32* __restrict__ cnt) {
    for (int e = blockIdx.x * blockDim.x + threadIdx.x; e < N_EDGES;
         e += gridDim.x * blockDim.x)
        atomicAdd(&cnt[ei[N_EDGES + e]], 1u);
}

#define CHUNK 1024
__global__ void k_scan1(const u32* __restrict__ cnt, u32* __restrict__ offs,
                        u32* __restrict__ part, float* __restrict__ dinv,
                        u32* __restrict__ curs) {
    __shared__ u32 sh[256];
    int t = threadIdx.x;
    int base = blockIdx.x * CHUNK + t * 4;
    u32 v[4];
    #pragma unroll
    for (int j = 0; j < 4; j++) v[j] = (base + j < N_NODES) ? cnt[base + j] : 0u;
    #pragma unroll
    for (int j = 0; j < 4; j++)
        if (base + j < N_NODES) {
            dinv[base + j] = rsqrtf((float)v[j] + 1.0f);
            curs[base + j] = 0u;
        }
    u32 s = v[0] + v[1] + v[2] + v[3];
    sh[t] = s;
    __syncthreads();
    for (int off = 1; off < 256; off <<= 1) {
        u32 val = (t >= off) ? sh[t - off] : 0u;
        __syncthreads();
        sh[t] += val;
        __syncthreads();
    }
    u32 run = sh[t] - s;
    #pragma unroll
    for (int j = 0; j < 4; j++) {
        if (base + j < N_NODES) offs[base + j] = run;
        run += v[j];
    }
    if (t == 255) part[blockIdx.x] = sh[255];
}

__global__ void k_scan2(u32* __restrict__ part, int n) {
    if (threadIdx.x != 0) return;
    u32 run = 0;
    for (int b = 0; b < n; b++) { u32 v = part[b]; part[b] = run; run += v; }
}

__global__ void k_scan3(u32* __restrict__ offs, const u32* __restrict__ part) {
    int i = blockIdx.x * blockDim.x + threadIdx.x;
    if (i < N_NODES) offs[i] += part[i >> 10];
    if (i == 0) offs[N_NODES] = N_EDGES;
}

__global__ void k_bin(const int* __restrict__ ei, const u32* __restrict__ offs,
                      u32* __restrict__ curs, u32* __restrict__ ebuf) {
    for (int e = blockIdx.x * blockDim.x + threadIdx.x; e < N_EDGES;
         e += gridDim.x * blockDim.x) {
        int c = ei[N_EDGES + e];
        u32 pos = offs[c] + atomicAdd(&curs[c], 1u);
        ebuf[pos] = (u32)ei[e];
    }
}

// ---------------- 5. xw = x @ W_new : bf16 MFMA 16x16x32, fragment-ordered LDS -----
// Block: 256 thr = 4 waves, tile M=64 (16 rows/wave), N=128, K=128.
// A layout per frag: A[m=lane&15][k=(lane>>4)*8+j]; B: B[k=(lane>>4)*8+j][n=lane&15];
// C/D: col=lane&15, row=(lane>>4)*4+reg  (per cdna_hip_programming §3, m89/m91).

__global__ __launch_bounds__(256) void k_gemm(const float* __restrict__ x,
                                              const u16* __restrict__ Bfrag,
                                              u16* __restrict__ xwh) {
    __shared__ __align__(16) u16 As[8192];    // [rowblk 4][kc 4][lane 64][j 8]
    __shared__ __align__(16) u16 Bs[16384];   // [nb 8][kc 4][lane 64][j 8]
    int t = threadIdx.x;
    int r0 = blockIdx.x * 64;
    // stage A: 64 rows x 128 f, fp32 -> bf16 fragment order
    #pragma unroll
    for (int i = 0; i < 8; i++) {
        int l = t + i * 256;              // 2048 float4s
        int row = l >> 5, c4 = l & 31;
        int f0 = c4 * 4;
        float4 v = {0.f, 0.f, 0.f, 0.f};
        if (r0 + row < N_NODES) v = *(const float4*)&x[(size_t)(r0 + row) * F + f0];
        int widx = (((row >> 4) * 4 + (f0 >> 5)) * 64 + ((f0 >> 3) & 3) * 16 + (row & 15)) * 8
                   + (f0 & 7);
        ushort4 s4;
        s4.x = f2bf(v.x); s4.y = f2bf(v.y); s4.z = f2bf(v.z); s4.w = f2bf(v.w);
        *(ushort4*)&As[widx] = s4;
    }
    // stage B: copy pre-packed fragment buffer (32 KB)
    #pragma unroll
    for (int i = 0; i < 8; i++) {
        int idx = t + i * 256;            // 2048 uint4s
        ((uint4*)Bs)[idx] = ((const uint4*)Bfrag)[idx];
    }
    __syncthreads();

    int wv = t >> 6, lane = t & 63;
    floatx4 acc[8] = {};
    #pragma unroll
    for (int kc = 0; kc < 4; kc++) {
        short8 a = *(const short8*)&As[((wv * 4 + kc) * 64 + lane) * 8];
        #pragma unroll
        for (int nb = 0; nb < 8; nb++) {
            short8 b = *(const short8*)&Bs[((nb * 4 + kc) * 64 + lane) * 8];
            acc[nb] = __builtin_amdgcn_mfma_f32_16x16x32_bf16(a, b, acc[nb], 0, 0, 0);
        }
    }
    int q = lane >> 4, m = lane & 15;
    #pragma unroll
    for (int nb = 0; nb < 8; nb++) {
        #pragma unroll
        for (int reg = 0; reg < 4; reg++) {
            int grow = r0 + wv * 16 + q * 4 + reg;
            if (grow < N_NODES)
                xwh[(size_t)grow * F + nb * 16 + m] = f2bf(acc[nb][reg]);
        }
    }
}

// ---------------- 6. gather-aggregate + fused head (bf16 xw, 8-deep MLP) ----------

__global__ void k_gather(const u32* __restrict__ xw32, const u32* __restrict__ offs,
                         const u32* __restrict__ ebuf, const float* __restrict__ dinv,
                         const float* __restrict__ conv_bias, const float* __restrict__ lin_w,
                         const float* __restrict__ lin_b, float* __restrict__ out) {
    int c = blockIdx.x * 4 + (threadIdx.x >> 6);
    if (c >= N_NODES) return;
    int lane = threadIdx.x & 63;
    u32 jbeg = offs[c], jend = offs[c + 1];
    float ax0 = 0.f, ax1 = 0.f, ax2 = 0.f, ax3 = 0.f;
    float ay0 = 0.f, ay1 = 0.f, ay2 = 0.f, ay3 = 0.f;
    u32 j = jbeg;
    for (; j + 8 <= jend; j += 8) {
        u32 r[8], b[8];
        float w[8];
        #pragma unroll
        for (int i = 0; i < 8; i++) r[i] = ebuf[j + i];
        #pragma unroll
        for (int i = 0; i < 8; i++) w[i] = dinv[r[i]];
        #pragma unroll
        for (int i = 0; i < 8; i++) b[i] = xw32[(size_t)r[i] * 64 + lane];
        ax0 += w[0] * __uint_as_float(b[0] << 16); ay0 += w[0] * __uint_as_float(b[0] & 0xffff0000u);
        ax1 += w[1] * __uint_as_float(b[1] << 16); ay1 += w[1] * __uint_as_float(b[1] & 0xffff0000u);
        ax2 += w[2] * __uint_as_float(b[2] << 16); ay2 += w[2] * __uint_as_float(b[2] & 0xffff0000u);
        ax3 += w[3] * __uint_as_float(b[3] << 16); ay3 += w[3] * __uint_as_float(b[3] & 0xffff0000u);
        ax0 += w[4] * __uint_as_float(b[4] << 16); ay0 += w[4] * __uint_as_float(b[4] & 0xffff0000u);
        ax1 += w[5] * __uint_as_float(b[5] << 16); ay1 += w[5] * __uint_as_float(b[5] & 0xffff0000u);
        ax2 += w[6] * __uint_as_float(b[6] << 16); ay2 += w[6] * __uint_as_float(b[6] & 0xffff0000u);
        ax3 += w[7] * __uint_as_float(b[7] << 16); ay3 += w[7] * __uint_as_float(b[7] & 0xffff0000u);
    }
    for (; j < jend; j++) {
        u32 r = ebuf[j];
        float wv = dinv[r];
        u32 b = xw32[(size_t)r * 64 + lane];
        ax0 += wv * __uint_as_float(b << 16);
        ay0 += wv * __uint_as_float(b & 0xffff0000u);
    }
    float accx = (ax0 + ax1) + (ax2 + ax3);
    float accy = (ay0 + ay1) + (ay2 + ay3);
    float dc = dinv[c];
    u32 sbits = xw32[(size_t)c * 64 + lane];
    float slo = __uint_as_float(sbits << 16);
    float shi = __uint_as_float(sbits & 0xffff0000u);
    accx = dc * accx + dc * dc * slo + conv_bias[lane * 2];
    accy = dc * accy + dc * dc * shi + conv_bias[lane * 2 + 1];
    float hx = fmaxf(accx, 0.f), hy = fmaxf(accy, 0.f);
    float part = hx * lin_w[lane * 2] + hy * lin_w[lane * 2 + 1];
    part = wave_reduce(part);
    if (lane == 0) out[c] = part + lin_b[0];
}

// ---------------- launch ----------------

extern "C" void kernel_launch(void* const* d_in, const int* in_sizes, int n_in,
                              void* d_out, int out_size, void* d_ws, size_t ws_size,
                              hipStream_t stream) {
    const float* x         = (const float*)d_in[0];
    const int*   ei        = (const int*)  d_in[1];
    const float* W         = (const float*)d_in[2];
    const float* p         = (const float*)d_in[3];
    const float* w_ih      = (const float*)d_in[4];
    const float* w_hh      = (const float*)d_in[5];
    const float* b_ih      = (const float*)d_in[6];
    const float* b_hh      = (const float*)d_in[7];
    const float* conv_bias = (const float*)d_in[8];
    const float* lin_w     = (const float*)d_in[9];
    const float* lin_b     = (const float*)d_in[10];
    float* out = (float*)d_out;

    u32*   w  = (u32*)d_ws;
    float* wf = (float*)d_ws;

    // ws layout (word offsets), ~34.4 MB total
    const size_t SCORES_W = 0;          // 100000
    const size_t DINV_W   = 100096;     // 100000
    const size_t CNT_W    = 200192;     // 100000
    const size_t OFFS_W   = 300288;     // 100001
    const size_t CURS_W   = 400416;     // 100000
    const size_t PART_W   = 500416;     // 128
    const size_t HIST_W   = 500608;     // 65536 bins (16-bit key histogram)
    const size_t STATE_W  = 566144;     // 8
    const size_t CAND_W   = 566160;     // 2048
    const size_t TOPI_W   = 568208;     // 128
    const size_t GATE_W   = 568336;     // 128
    const size_t WNEW_W   = 568464;     // 16384
    const size_t BFRAG_W  = 584848;     // 8192 (bf16 fragment-ordered W_new)
    const size_t EBUF_W   = 593040;     // 1600000
    const size_t XW_W     = 2193040;    // bf16 xw: 6400000 words

    float* scores  = wf + SCORES_W;
    float* dinv    = wf + DINV_W;
    u32*   cnt     = w  + CNT_W;
    u32*   offs    = w  + OFFS_W;
    u32*   curs    = w  + CURS_W;
    u32*   part    = w  + PART_W;
    u32*   hist16  = w  + HIST_W;
    u32*   state   = w  + STATE_W;
    u32*   cand    = w  + CAND_W;
    u32*   top_idx = w  + TOPI_W;
    float* gate    = wf + GATE_W;
    float* Wnew    = wf + WNEW_W;
    u16*   Bfrag   = (u16*)(w + BFRAG_W);
    u32*   ebuf    = w  + EBUF_W;
    u16*   xwh     = (u16*)(w + XW_W);
    u32*   xw32    = w + XW_W;

    hipMemsetAsync(cnt, 0, N_NODES * sizeof(u32), stream);
    hipMemsetAsync(hist16, 0, (65536 + 8) * sizeof(u32), stream);  // hist16 + state

    k_scores<<<25000, 256, 0, stream>>>(x, p, scores);
    k_hist16<<<392, 256, 0, stream>>>(scores, hist16);
    k_scan16<<<1, 1024, 0, stream>>>(hist16, state);
    k_collect16<<<392, 256, 0, stream>>>(scores, state, cand);
    k_assemble16<<<1, 256, 0, stream>>>(scores, p, state, cand, top_idx, gate);
    k_gru<<<128, 256, 0, stream>>>(x, W, w_ih, w_hh, b_ih, b_hh, top_idx, gate,
                                   Wnew, Bfrag);

    k_count<<<1024, 256, 0, stream>>>(ei, cnt);
    k_scan1<<<98, 256, 0, stream>>>(cnt, offs, part, dinv, curs);
    k_scan2<<<1, 64, 0, stream>>>(part, 98);
    k_scan3<<<(N_NODES + 255) / 256, 256, 0, stream>>>(offs, part);
    k_bin<<<1024, 256, 0, stream>>>(ei, offs, curs, ebuf);

    k_gemm<<<1563, 256, 0, stream>>>(x, Bfrag, xwh);

    k_gather<<<25000, 256, 0, stream>>>(xw32, offs, ebuf, dinv, conv_bias, lin_w,
                                        lin_b, out);
}

// Round 5
// 440.175 us; speedup vs baseline: 1.4742x; 1.2575x over previous
//
#include <hip/hip_runtime.h>
#include <math.h>

#define N_NODES 100000
#define N_EDGES 1600000
#define F 128

typedef unsigned int u32;
typedef unsigned short u16;
typedef __attribute__((ext_vector_type(8))) short short8;
typedef __attribute__((ext_vector_type(4))) float floatx4;

// ---------------- helpers ----------------

__device__ __forceinline__ u32 key_of(float s) {
    u32 u = __float_as_uint(s);
    return (u & 0x80000000u) ? ~u : (u | 0x80000000u);   // larger float -> larger key
}

__device__ __forceinline__ float wave_reduce(float v) {
    #pragma unroll
    for (int off = 32; off > 0; off >>= 1) v += __shfl_down(v, off, 64);
    return v;
}

__device__ __forceinline__ u16 f2bf(float f) {   // round-to-nearest-even
    u32 u = __float_as_uint(f);
    u += 0x7fffu + ((u >> 16) & 1u);
    return (u16)(u >> 16);
}

// ---------------- 1. scores[i] = x[i] . p  (selection is scale-invariant) ----------

__global__ void k_scores(const float* __restrict__ x, const float* __restrict__ p,
                         float* __restrict__ scores) {
    int node = blockIdx.x * 4 + (threadIdx.x >> 6);
    int lane = threadIdx.x & 63;
    if (node >= N_NODES) return;
    float2 xv = *(const float2*)&x[(size_t)node * F + lane * 2];
    float2 pv = *(const float2*)&p[lane * 2];
    float d = xv.x * pv.x + xv.y * pv.y;
    d = wave_reduce(d);
    if (lane == 0) scores[node] = d;
}

// ---------------- 2. top-128: one 16-bit histogram pass + exact candidate sort ------

__global__ void k_hist16(const float* __restrict__ scores, u32* __restrict__ hist16) {
    int i = blockIdx.x * blockDim.x + threadIdx.x;
    if (i < N_NODES) atomicAdd(&hist16[key_of(scores[i]) >> 16], 1u);
}

__global__ __launch_bounds__(1024) void k_scan16(const u32* __restrict__ hist16,
                                                 u32* __restrict__ state) {
    __shared__ u32 a[1024];
    int t = threadIdx.x;
    const uint4* h4 = (const uint4*)hist16;
    u32 local = 0;
    #pragma unroll
    for (int i = 0; i < 16; i++) {
        uint4 v = h4[t * 16 + i];
        local += v.x + v.y + v.z + v.w;
    }
    a[t] = local;
    __syncthreads();
    for (int off = 1; off < 1024; off <<= 1) {
        u32 add = (t + off < 1024) ? a[t + off] : 0u;
        __syncthreads();
        a[t] += add;
        __syncthreads();
    }
    u32 S_above = (t == 1023) ? 0u : a[t + 1];
    if (S_above < 128u && a[t] >= 128u) {     // threshold bucket is in my chunk
        u32 cum = S_above;
        for (int v = t * 64 + 63; v >= t * 64; v--) {
            cum += hist16[v];
            if (cum >= 128u) { state[0] = (u32)v; break; }
        }
    }
}

__global__ void k_collect16(const float* __restrict__ scores, u32* __restrict__ state,
                            u32* __restrict__ cand) {
    u32 T = state[0] << 16;
    int i = blockIdx.x * blockDim.x + threadIdx.x;
    if (i < N_NODES) {
        if (key_of(scores[i]) >= T) {
            u32 pos = atomicAdd(&state[2], 1u);
            if (pos < 2048u) cand[pos] = (u32)i;
        }
    }
}

__global__ void k_assemble16(const float* __restrict__ scores, const float* __restrict__ p,
                             const u32* __restrict__ state, const u32* __restrict__ cand,
                             u32* __restrict__ top_idx, float* __restrict__ gate) {
    __shared__ u32 ci[2048];
    __shared__ float csc[2048];
    __shared__ float s_inv;
    int t = threadIdx.x;   // 256 threads
    if (t < 64) {
        float2 pv = *(const float2*)&p[t * 2];
        float d = pv.x * pv.x + pv.y * pv.y;
        d = wave_reduce(d);
        if (t == 0) s_inv = rsqrtf(d);
    }
    u32 nc = state[2]; if (nc > 2048u) nc = 2048u;
    for (u32 i = t; i < nc; i += 256) { u32 ix = cand[i]; ci[i] = ix; csc[i] = scores[ix]; }
    __syncthreads();
    for (u32 i = t; i < nc; i += 256) {
        u32 myk = key_of(csc[i]);
        u32 myi = ci[i];
        int rank = 0;
        for (u32 j = 0; j < nc; j++) {
            u32 ok = key_of(csc[j]);
            rank += (int)((ok > myk) || (ok == myk && ci[j] < myi));
        }
        if (rank < 128) {   // exact jax semantics: value desc, index asc on ties
            top_idx[rank] = myi;
            gate[rank] = tanhf(csc[i] * s_inv);
        }
    }
}

// ---------------- 3a. GRU GEMMs: g[128][768] = [x_tilde | W] . [w_ih | w_hh]^T -----
// Tiles: 32 k-rows x 64 j-cols, grid (4, 12). fp32 VALU, LDS-staged.

__global__ __launch_bounds__(256) void k_ggemm(const float* __restrict__ x,
                                               const float* __restrict__ W,
                                               const float* __restrict__ w_ih,
                                               const float* __restrict__ w_hh,
                                               const u32* __restrict__ top_idx,
                                               const float* __restrict__ gate,
                                               float* __restrict__ G) {
    __shared__ float As[32][128];       // A reads broadcast per row -> no pad needed
    __shared__ float Bs[64][131];       // pad 131: (6*tx+3i+f)%32, 2-way max (free)
    int t = threadIdx.x;
    int k0 = blockIdx.x * 32;
    int by = blockIdx.y;                // 0..11; <6 -> gi (w_ih, x_tilde), else gh
    int j0 = by * 64;
    bool is_gi = (by < 6);
    // stage A (32 rows x 128)
    #pragma unroll
    for (int i = 0; i < 4; i++) {
        int l = t + i * 256;            // 1024 float4s
        int row = l >> 5, c4 = l & 31;
        float4 v;
        if (is_gi) {
            u32 idx = top_idx[k0 + row];
            float gt = gate[k0 + row];
            v = *(const float4*)&x[(size_t)idx * F + c4 * 4];
            v.x *= gt; v.y *= gt; v.z *= gt; v.w *= gt;
        } else {
            v = *(const float4*)&W[(k0 + row) * F + c4 * 4];
        }
        *(float4*)&As[row][c4 * 4] = v;
    }
    // stage B (64 rows x 128)
    const float* mat = is_gi ? w_ih : w_hh;
    int jbase = is_gi ? j0 : (j0 - 384);
    #pragma unroll
    for (int i = 0; i < 8; i++) {
        int l = t + i * 256;            // 2048 float4s
        int row = l >> 5, c4 = l & 31;
        float4 v = *(const float4*)&mat[(jbase + row) * F + c4 * 4];
        Bs[row][c4 * 4 + 0] = v.x; Bs[row][c4 * 4 + 1] = v.y;
        Bs[row][c4 * 4 + 2] = v.z; Bs[row][c4 * 4 + 3] = v.w;
    }
    __syncthreads();
    int ty = t >> 5;                    // 8 groups -> rows ty*4..+3
    int tx = t & 31;                    // cols tx*2, tx*2+1
    float acc[4][2] = {};
    #pragma unroll 4
    for (int f = 0; f < 128; f++) {
        float b0 = Bs[tx * 2][f], b1 = Bs[tx * 2 + 1][f];
        #pragma unroll
        for (int i = 0; i < 4; i++) {
            float a = As[ty * 4 + i][f];
            acc[i][0] += a * b0;
            acc[i][1] += a * b1;
        }
    }
    #pragma unroll
    for (int i = 0; i < 4; i++) {
        int k = k0 + ty * 4 + i;
        G[(size_t)k * 768 + j0 + tx * 2 + 0] = acc[i][0];
        G[(size_t)k * 768 + j0 + tx * 2 + 1] = acc[i][1];
    }
}

// ---------------- 3b. pointwise GRU gates -> Wnew + fragment-ordered bf16 B --------

__global__ void k_gate(const float* __restrict__ G, const float* __restrict__ W,
                       const float* __restrict__ b_ih, const float* __restrict__ b_hh,
                       float* __restrict__ Wnew, u16* __restrict__ Bfrag) {
    int idx = blockIdx.x * blockDim.x + threadIdx.x;   // 16384
    int k = idx >> 7, h = idx & 127;
    const float* gk = &G[(size_t)k * 768];
    float gir = gk[h]       + b_ih[h];
    float giz = gk[128 + h] + b_ih[128 + h];
    float gin = gk[256 + h] + b_ih[256 + h];
    float ghr = gk[384 + h] + b_hh[h];
    float ghz = gk[512 + h] + b_hh[128 + h];
    float ghn = gk[640 + h] + b_hh[256 + h];
    float wv  = W[k * F + h];
    float rg = 1.0f / (1.0f + expf(-(gir + ghr)));
    float z  = 1.0f / (1.0f + expf(-(giz + ghz)));
    float n  = tanhf(gin + rg * ghn);
    float val = (1.0f - z) * n + z * wv;
    Wnew[k * F + h] = val;
    int nb = h >> 4, kc = k >> 5, q = (k >> 3) & 3, m = h & 15, jj = k & 7;
    Bfrag[(((nb * 4 + kc) * 64) + q * 16 + m) * 8 + jj] = f2bf(val);
}

// ---------------- 4. degree count / CSR build (XCD-range partitioned) ----------
// blockIdx&7 selects a destination range (heuristic: round-robin wg->XCD), so each
// XCD's L2 owns a contiguous 1/8 of cnt/curs/ebuf -> full-line writebacks.

#define ESLICE 12500   // N_EDGES / 128
#define NRANGE 12500   // N_NODES / 8

__global__ void k_count(const int* __restrict__ ei, u32* __restrict__ cnt) {
    int range = blockIdx.x & 7, slice = blockIdx.x >> 3;
    int lo = range * NRANGE, hi = lo + NRANGE;
    int e0 = slice * ESLICE;
    for (int e = e0 + threadIdx.x; e < e0 + ESLICE; e += 256) {
        int c = ei[N_EDGES + e];
        if (c >= lo && c < hi) atomicAdd(&cnt[c], 1u);
    }
}

#define CHUNK 1024
__global__ void k_scan1(const u32* __restrict__ cnt, u32* __restrict__ offs,
                        u32* __restrict__ part, float* __restrict__ dinv,
                        u32* __restrict__ curs) {
    __shared__ u32 sh[256];
    int t = threadIdx.x;
    int base = blockIdx.x * CHUNK + t * 4;
    u32 v[4];
    #pragma unroll
    for (int j = 0; j < 4; j++) v[j] = (base + j < N_NODES) ? cnt[base + j] : 0u;
    #pragma unroll
    for (int j = 0; j < 4; j++)
        if (base + j < N_NODES) {
            dinv[base + j] = rsqrtf((float)v[j] + 1.0f);
            curs[base + j] = 0u;
        }
    u32 s = v[0] + v[1] + v[2] + v[3];
    sh[t] = s;
    __syncthreads();
    for (int off = 1; off < 256; off <<= 1) {
        u32 val = (t >= off) ? sh[t - off] : 0u;
        __syncthreads();
        sh[t] += val;
        __syncthreads();
    }
    u32 run = sh[t] - s;
    #pragma unroll
    for (int j = 0; j < 4; j++) {
        if (base + j < N_NODES) offs[base + j] = run;
        run += v[j];
    }
    if (t == 255) part[blockIdx.x] = sh[255];
}

__global__ void k_scan2(u32* __restrict__ part, int n) {
    if (threadIdx.x != 0) return;
    u32 run = 0;
    for (int b = 0; b < n; b++) { u32 v = part[b]; part[b] = run; run += v; }
}

__global__ void k_scan3(u32* __restrict__ offs, const u32* __restrict__ part) {
    int i = blockIdx.x * blockDim.x + threadIdx.x;
    if (i < N_NODES) offs[i] += part[i >> 10];
    if (i == 0) offs[N_NODES] = N_EDGES;
}

__global__ void k_bin(const int* __restrict__ ei, const u32* __restrict__ offs,
                      u32* __restrict__ curs, u32* __restrict__ ebuf) {
    int range = blockIdx.x & 7, slice = blockIdx.x >> 3;
    int lo = range * NRANGE, hi = lo + NRANGE;
    int e0 = slice * ESLICE;
    for (int e = e0 + threadIdx.x; e < e0 + ESLICE; e += 256) {
        int c = ei[N_EDGES + e];
        if (c >= lo && c < hi) {
            u32 pos = offs[c] + atomicAdd(&curs[c], 1u);
            ebuf[pos] = (u32)ei[e];
        }
    }
}

// ---------------- 5. xw = x @ W_new : bf16 MFMA 16x16x32, fragment-ordered LDS -----

__global__ __launch_bounds__(256) void k_gemm(const float* __restrict__ x,
                                              const u16* __restrict__ Bfrag,
                                              u16* __restrict__ xwh) {
    __shared__ __align__(16) u16 As[8192];    // [rowblk 4][kc 4][lane 64][j 8]
    __shared__ __align__(16) u16 Bs[16384];   // [nb 8][kc 4][lane 64][j 8]
    int t = threadIdx.x;
    int r0 = blockIdx.x * 64;
    #pragma unroll
    for (int i = 0; i < 8; i++) {
        int l = t + i * 256;              // 2048 float4s
        int row = l >> 5, c4 = l & 31;
        int f0 = c4 * 4;
        float4 v = {0.f, 0.f, 0.f, 0.f};
        if (r0 + row < N_NODES) v = *(const float4*)&x[(size_t)(r0 + row) * F + f0];
        int widx = (((row >> 4) * 4 + (f0 >> 5)) * 64 + ((f0 >> 3) & 3) * 16 + (row & 15)) * 8
                   + (f0 & 7);
        ushort4 s4;
        s4.x = f2bf(v.x); s4.y = f2bf(v.y); s4.z = f2bf(v.z); s4.w = f2bf(v.w);
        *(ushort4*)&As[widx] = s4;
    }
    #pragma unroll
    for (int i = 0; i < 8; i++) {
        int idx = t + i * 256;            // 2048 uint4s
        ((uint4*)Bs)[idx] = ((const uint4*)Bfrag)[idx];
    }
    __syncthreads();

    int wv = t >> 6, lane = t & 63;
    floatx4 acc[8] = {};
    #pragma unroll
    for (int kc = 0; kc < 4; kc++) {
        short8 a = *(const short8*)&As[((wv * 4 + kc) * 64 + lane) * 8];
        #pragma unroll
        for (int nb = 0; nb < 8; nb++) {
            short8 b = *(const short8*)&Bs[((nb * 4 + kc) * 64 + lane) * 8];
            acc[nb] = __builtin_amdgcn_mfma_f32_16x16x32_bf16(a, b, acc[nb], 0, 0, 0);
        }
    }
    int q = lane >> 4, m = lane & 15;
    #pragma unroll
    for (int nb = 0; nb < 8; nb++) {
        #pragma unroll
        for (int reg = 0; reg < 4; reg++) {
            int grow = r0 + wv * 16 + q * 4 + reg;
            if (grow < N_NODES)
                xwh[(size_t)grow * F + nb * 16 + m] = f2bf(acc[nb][reg]);
        }
    }
}

// ---------------- 6. gather-aggregate + fused head (bf16 xw, 8-deep MLP) ----------

__global__ void k_gather(const u32* __restrict__ xw32, const u32* __restrict__ offs,
                         const u32* __restrict__ ebuf, const float* __restrict__ dinv,
                         const float* __restrict__ conv_bias, const float* __restrict__ lin_w,
                         const float* __restrict__ lin_b, float* __restrict__ out) {
    int c = blockIdx.x * 4 + (threadIdx.x >> 6);
    if (c >= N_NODES) return;
    int lane = threadIdx.x & 63;
    u32 jbeg = offs[c], jend = offs[c + 1];
    float ax0 = 0.f, ax1 = 0.f, ax2 = 0.f, ax3 = 0.f;
    float ay0 = 0.f, ay1 = 0.f, ay2 = 0.f, ay3 = 0.f;
    u32 j = jbeg;
    for (; j + 8 <= jend; j += 8) {
        u32 r[8], b[8];
        float w[8];
        #pragma unroll
        for (int i = 0; i < 8; i++) r[i] = ebuf[j + i];
        #pragma unroll
        for (int i = 0; i < 8; i++) w[i] = dinv[r[i]];
        #pragma unroll
        for (int i = 0; i < 8; i++) b[i] = xw32[(size_t)r[i] * 64 + lane];
        ax0 += w[0] * __uint_as_float(b[0] << 16); ay0 += w[0] * __uint_as_float(b[0] & 0xffff0000u);
        ax1 += w[1] * __uint_as_float(b[1] << 16); ay1 += w[1] * __uint_as_float(b[1] & 0xffff0000u);
        ax2 += w[2] * __uint_as_float(b[2] << 16); ay2 += w[2] * __uint_as_float(b[2] & 0xffff0000u);
        ax3 += w[3] * __uint_as_float(b[3] << 16); ay3 += w[3] * __uint_as_float(b[3] & 0xffff0000u);
        ax0 += w[4] * __uint_as_float(b[4] << 16); ay0 += w[4] * __uint_as_float(b[4] & 0xffff0000u);
        ax1 += w[5] * __uint_as_float(b[5] << 16); ay1 += w[5] * __uint_as_float(b[5] & 0xffff0000u);
        ax2 += w[6] * __uint_as_float(b[6] << 16); ay2 += w[6] * __uint_as_float(b[6] & 0xffff0000u);
        ax3 += w[7] * __uint_as_float(b[7] << 16); ay3 += w[7] * __uint_as_float(b[7] & 0xffff0000u);
    }
    for (; j < jend; j++) {
        u32 r = ebuf[j];
        float wv = dinv[r];
        u32 b = xw32[(size_t)r * 64 + lane];
        ax0 += wv * __uint_as_float(b << 16);
        ay0 += wv * __uint_as_float(b & 0xffff0000u);
    }
    float accx = (ax0 + ax1) + (ax2 + ax3);
    float accy = (ay0 + ay1) + (ay2 + ay3);
    float dc = dinv[c];
    u32 sbits = xw32[(size_t)c * 64 + lane];
    float slo = __uint_as_float(sbits << 16);
    float shi = __uint_as_float(sbits & 0xffff0000u);
    accx = dc * accx + dc * dc * slo + conv_bias[lane * 2];
    accy = dc * accy + dc * dc * shi + conv_bias[lane * 2 + 1];
    float hx = fmaxf(accx, 0.f), hy = fmaxf(accy, 0.f);
    float part = hx * lin_w[lane * 2] + hy * lin_w[lane * 2 + 1];
    part = wave_reduce(part);
    if (lane == 0) out[c] = part + lin_b[0];
}

// ---------------- launch ----------------

extern "C" void kernel_launch(void* const* d_in, const int* in_sizes, int n_in,
                              void* d_out, int out_size, void* d_ws, size_t ws_size,
                              hipStream_t stream) {
    const float* x         = (const float*)d_in[0];
    const int*   ei        = (const int*)  d_in[1];
    const float* W         = (const float*)d_in[2];
    const float* p         = (const float*)d_in[3];
    const float* w_ih      = (const float*)d_in[4];
    const float* w_hh      = (const float*)d_in[5];
    const float* b_ih      = (const float*)d_in[6];
    const float* b_hh      = (const float*)d_in[7];
    const float* conv_bias = (const float*)d_in[8];
    const float* lin_w     = (const float*)d_in[9];
    const float* lin_b     = (const float*)d_in[10];
    float* out = (float*)d_out;

    u32*   w  = (u32*)d_ws;
    float* wf = (float*)d_ws;

    // ws layout (word offsets), ~34.4 MB total. G overlays EBUF (dead before k_count).
    const size_t SCORES_W = 0;          // 100000
    const size_t DINV_W   = 100096;     // 100000
    const size_t CNT_W    = 200192;     // 100000
    const size_t OFFS_W   = 300288;     // 100001
    const size_t CURS_W   = 400416;     // 100000
    const size_t PART_W   = 500416;     // 128
    const size_t HIST_W   = 500608;     // 65536
    const size_t STATE_W  = 566144;     // 8
    const size_t CAND_W   = 566160;     // 2048
    const size_t TOPI_W   = 568208;     // 128
    const size_t GATE_W   = 568336;     // 128
    const size_t WNEW_W   = 568464;     // 16384
    const size_t BFRAG_W  = 584848;     // 8192 words (16384 bf16)
    const size_t EBUF_W   = 593040;     // 1600000  (also G: 98304 words, earlier phase)
    const size_t XW_W     = 2193040;    // bf16 xw: 6400000 words

    float* scores  = wf + SCORES_W;
    float* dinv    = wf + DINV_W;
    u32*   cnt     = w  + CNT_W;
    u32*   offs    = w  + OFFS_W;
    u32*   curs    = w  + CURS_W;
    u32*   part    = w  + PART_W;
    u32*   hist16  = w  + HIST_W;
    u32*   state   = w  + STATE_W;
    u32*   cand    = w  + CAND_W;
    u32*   top_idx = w  + TOPI_W;
    float* gate    = wf + GATE_W;
    float* Wnew    = wf + WNEW_W;
    u16*   Bfrag   = (u16*)(w + BFRAG_W);
    float* G       = wf + EBUF_W;       // overlay
    u32*   ebuf    = w  + EBUF_W;
    u16*   xwh     = (u16*)(w + XW_W);
    u32*   xw32    = w + XW_W;

    hipMemsetAsync(cnt, 0, N_NODES * sizeof(u32), stream);
    hipMemsetAsync(hist16, 0, (65536 + 8) * sizeof(u32), stream);  // hist16 + state

    k_scores<<<25000, 256, 0, stream>>>(x, p, scores);
    k_hist16<<<392, 256, 0, stream>>>(scores, hist16);
    k_scan16<<<1, 1024, 0, stream>>>(hist16, state);
    k_collect16<<<392, 256, 0, stream>>>(scores, state, cand);
    k_assemble16<<<1, 256, 0, stream>>>(scores, p, state, cand, top_idx, gate);
    k_ggemm<<<dim3(4, 12), 256, 0, stream>>>(x, W, w_ih, w_hh, top_idx, gate, G);
    k_gate<<<64, 256, 0, stream>>>(G, W, b_ih, b_hh, Wnew, Bfrag);

    k_count<<<1024, 256, 0, stream>>>(ei, cnt);
    k_scan1<<<98, 256, 0, stream>>>(cnt, offs, part, dinv, curs);
    k_scan2<<<1, 64, 0, stream>>>(part, 98);
    k_scan3<<<(N_NODES + 255) / 256, 256, 0, stream>>>(offs, part);
    k_bin<<<1024, 256, 0, stream>>>(ei, offs, curs, ebuf);

    k_gemm<<<1563, 256, 0, stream>>>(x, Bfrag, xwh);

    k_gather<<<25000, 256, 0, stream>>>(xw32, offs, ebuf, dinv, conv_bias, lin_w,
                                        lin_b, out);
}

// Round 6
// 363.639 us; speedup vs baseline: 1.7845x; 1.2105x over previous
//
#include <hip/hip_runtime.h>
#include <math.h>

#define N_NODES 100000
#define N_EDGES 1600000
#define F 128

// CSR radix: buckets of 512 destination nodes
#define BSH 9
#define NBUCK 196          // ceil(100000 / 512)
#define PB_EDGES 4096      // edges per k_part block

typedef unsigned int u32;
typedef unsigned long long u64;
typedef unsigned short u16;
typedef __attribute__((ext_vector_type(8))) short short8;
typedef __attribute__((ext_vector_type(4))) float floatx4;

// ---------------- helpers ----------------

__device__ __forceinline__ u32 key_of(float s) {
    u32 u = __float_as_uint(s);
    return (u & 0x80000000u) ? ~u : (u | 0x80000000u);   // larger float -> larger key
}

__device__ __forceinline__ float wave_reduce(float v) {
    #pragma unroll
    for (int off = 32; off > 0; off >>= 1) v += __shfl_down(v, off, 64);
    return v;
}

__device__ __forceinline__ u16 f2bf(float f) {   // round-to-nearest-even
    u32 u = __float_as_uint(f);
    u += 0x7fffu + ((u >> 16) & 1u);
    return (u16)(u >> 16);
}

// ---------------- 1. scores[i] = x[i] . p  (+ fused 16-bit key histogram) ----------

__global__ void k_scores(const float* __restrict__ x, const float* __restrict__ p,
                         float* __restrict__ scores, u32* __restrict__ hist16) {
    int node = blockIdx.x * 4 + (threadIdx.x >> 6);
    int lane = threadIdx.x & 63;
    if (node >= N_NODES) return;
    float2 xv = *(const float2*)&x[(size_t)node * F + lane * 2];
    float2 pv = *(const float2*)&p[lane * 2];
    float d = xv.x * pv.x + xv.y * pv.y;
    d = wave_reduce(d);
    if (lane == 0) {
        scores[node] = d;
        atomicAdd(&hist16[key_of(d) >> 16], 1u);
    }
}

// ---------------- 2. top-128 select ----------------

__global__ __launch_bounds__(1024) void k_scan16(const u32* __restrict__ hist16,
                                                 u32* __restrict__ state) {
    __shared__ u32 a[1024];
    int t = threadIdx.x;
    const uint4* h4 = (const uint4*)hist16;
    u32 local = 0;
    #pragma unroll
    for (int i = 0; i < 16; i++) {
        uint4 v = h4[t * 16 + i];
        local += v.x + v.y + v.z + v.w;
    }
    a[t] = local;
    __syncthreads();
    for (int off = 1; off < 1024; off <<= 1) {
        u32 add = (t + off < 1024) ? a[t + off] : 0u;
        __syncthreads();
        a[t] += add;
        __syncthreads();
    }
    u32 S_above = (t == 1023) ? 0u : a[t + 1];
    if (S_above < 128u && a[t] >= 128u) {     // threshold bucket is in my chunk
        u32 cum = S_above;
        for (int v = t * 64 + 63; v >= t * 64; v--) {
            cum += hist16[v];
            if (cum >= 128u) { state[0] = (u32)v; break; }
        }
    }
}

__global__ void k_collect16(const float* __restrict__ scores, u32* __restrict__ state,
                            u32* __restrict__ cand) {
    u32 T = state[0] << 16;
    int i = blockIdx.x * blockDim.x + threadIdx.x;
    if (i < N_NODES) {
        if (key_of(scores[i]) >= T) {
            u32 pos = atomicAdd(&state[2], 1u);
            if (pos < 2048u) cand[pos] = (u32)i;
        }
    }
}

__global__ void k_assemble16(const float* __restrict__ scores, const float* __restrict__ p,
                             const u32* __restrict__ state, const u32* __restrict__ cand,
                             u32* __restrict__ top_idx, float* __restrict__ gate) {
    __shared__ u32 ci[2048];
    __shared__ float csc[2048];
    __shared__ float s_inv;
    int t = threadIdx.x;   // 256 threads
    if (t < 64) {
        float2 pv = *(const float2*)&p[t * 2];
        float d = pv.x * pv.x + pv.y * pv.y;
        d = wave_reduce(d);
        if (t == 0) s_inv = rsqrtf(d);
    }
    u32 nc = state[2]; if (nc > 2048u) nc = 2048u;
    for (u32 i = t; i < nc; i += 256) { u32 ix = cand[i]; ci[i] = ix; csc[i] = scores[ix]; }
    __syncthreads();
    for (u32 i = t; i < nc; i += 256) {
        u32 myk = key_of(csc[i]);
        u32 myi = ci[i];
        int rank = 0;
        for (u32 j = 0; j < nc; j++) {
            u32 ok = key_of(csc[j]);
            rank += (int)((ok > myk) || (ok == myk && ci[j] < myi));
        }
        if (rank < 128) {   // exact jax semantics: value desc, index asc on ties
            top_idx[rank] = myi;
            gate[rank] = tanhf(csc[i] * s_inv);
        }
    }
}

// ---------------- 3a. GRU GEMMs: g[128][768] = [x_tilde | W] . [w_ih | w_hh]^T -----

__global__ __launch_bounds__(256) void k_ggemm(const float* __restrict__ x,
                                               const float* __restrict__ W,
                                               const float* __restrict__ w_ih,
                                               const float* __restrict__ w_hh,
                                               const u32* __restrict__ top_idx,
                                               const float* __restrict__ gate,
                                               float* __restrict__ G) {
    __shared__ float As[32][128];
    __shared__ float Bs[64][131];
    int t = threadIdx.x;
    int k0 = blockIdx.x * 32;
    int by = blockIdx.y;                // 0..11; <6 -> gi (w_ih, x_tilde), else gh
    int j0 = by * 64;
    bool is_gi = (by < 6);
    #pragma unroll
    for (int i = 0; i < 4; i++) {
        int l = t + i * 256;
        int row = l >> 5, c4 = l & 31;
        float4 v;
        if (is_gi) {
            u32 idx = top_idx[k0 + row];
            float gt = gate[k0 + row];
            v = *(const float4*)&x[(size_t)idx * F + c4 * 4];
            v.x *= gt; v.y *= gt; v.z *= gt; v.w *= gt;
        } else {
            v = *(const float4*)&W[(k0 + row) * F + c4 * 4];
        }
        *(float4*)&As[row][c4 * 4] = v;
    }
    const float* mat = is_gi ? w_ih : w_hh;
    int jbase = is_gi ? j0 : (j0 - 384);
    #pragma unroll
    for (int i = 0; i < 8; i++) {
        int l = t + i * 256;
        int row = l >> 5, c4 = l & 31;
        float4 v = *(const float4*)&mat[(jbase + row) * F + c4 * 4];
        Bs[row][c4 * 4 + 0] = v.x; Bs[row][c4 * 4 + 1] = v.y;
        Bs[row][c4 * 4 + 2] = v.z; Bs[row][c4 * 4 + 3] = v.w;
    }
    __syncthreads();
    int ty = t >> 5, tx = t & 31;
    float acc[4][2] = {};
    #pragma unroll 4
    for (int f = 0; f < 128; f++) {
        float b0 = Bs[tx * 2][f], b1 = Bs[tx * 2 + 1][f];
        #pragma unroll
        for (int i = 0; i < 4; i++) {
            float a = As[ty * 4 + i][f];
            acc[i][0] += a * b0;
            acc[i][1] += a * b1;
        }
    }
    #pragma unroll
    for (int i = 0; i < 4; i++) {
        int k = k0 + ty * 4 + i;
        G[(size_t)k * 768 + j0 + tx * 2 + 0] = acc[i][0];
        G[(size_t)k * 768 + j0 + tx * 2 + 1] = acc[i][1];
    }
}

// ---------------- 3b. pointwise GRU gates -> Wnew + fragment-ordered bf16 B --------

__global__ void k_gate(const float* __restrict__ G, const float* __restrict__ W,
                       const float* __restrict__ b_ih, const float* __restrict__ b_hh,
                       float* __restrict__ Wnew, u16* __restrict__ Bfrag) {
    int idx = blockIdx.x * blockDim.x + threadIdx.x;   // 16384
    int k = idx >> 7, h = idx & 127;
    const float* gk = &G[(size_t)k * 768];
    float gir = gk[h]       + b_ih[h];
    float giz = gk[128 + h] + b_ih[128 + h];
    float gin = gk[256 + h] + b_ih[256 + h];
    float ghr = gk[384 + h] + b_hh[h];
    float ghz = gk[512 + h] + b_hh[128 + h];
    float ghn = gk[640 + h] + b_hh[256 + h];
    float wv  = W[k * F + h];
    float rg = 1.0f / (1.0f + expf(-(gir + ghr)));
    float z  = 1.0f / (1.0f + expf(-(giz + ghz)));
    float n  = tanhf(gin + rg * ghn);
    float val = (1.0f - z) * n + z * wv;
    Wnew[k * F + h] = val;
    int nb = h >> 4, kc = k >> 5, q = (k >> 3) & 3, m = h & 15, jj = k & 7;
    Bfrag[(((nb * 4 + kc) * 64) + q * 16 + m) * 8 + jj] = f2bf(val);
}

// ---------------- 4. CSR build: two-level radix scatter ----------------
// Level 1: partition edges into 196 dst-buckets (512 nodes each) as (dst,src) pairs.
// Level 2: per-bucket local CSR with LDS histogram/cursors -> offs, dinv, ebuf.

__global__ void k_bhist(const int* __restrict__ ei, u32* __restrict__ bhist) {
    __shared__ u32 h[NBUCK];
    int t = threadIdx.x;
    for (int i = t; i < NBUCK; i += 256) h[i] = 0u;
    __syncthreads();
    for (int e = blockIdx.x * blockDim.x + t; e < N_EDGES; e += gridDim.x * blockDim.x)
        atomicAdd(&h[((u32)ei[N_EDGES + e]) >> BSH], 1u);
    __syncthreads();
    for (int i = t; i < NBUCK; i += 256) if (h[i]) atomicAdd(&bhist[i], h[i]);
}

__global__ void k_bscan(const u32* __restrict__ bhist, u32* __restrict__ bbase,
                        u32* __restrict__ gcur) {
    __shared__ u32 s[256];
    int t = threadIdx.x;
    u32 v = (t < NBUCK) ? bhist[t] : 0u;
    s[t] = v;
    __syncthreads();
    for (int off = 1; off < 256; off <<= 1) {
        u32 add = (t >= off) ? s[t - off] : 0u;
        __syncthreads();
        s[t] += add;
        __syncthreads();
    }
    u32 excl = s[t] - v;
    if (t < NBUCK) { bbase[t] = excl; gcur[t] = excl; }
    if (t == 0) bbase[NBUCK] = N_EDGES;
}

__global__ void k_part(const int* __restrict__ ei, u32* __restrict__ gcur,
                       u64* __restrict__ pairs) {
    __shared__ u32 lh[NBUCK];     // local histogram, then local cursor
    __shared__ u32 lbase[NBUCK];  // reserved global base per bucket
    int t = threadIdx.x;
    int e0 = blockIdx.x * PB_EDGES;
    int e1 = e0 + PB_EDGES; if (e1 > N_EDGES) e1 = N_EDGES;
    for (int i = t; i < NBUCK; i += 256) lh[i] = 0u;
    __syncthreads();
    for (int e = e0 + t; e < e1; e += 256)
        atomicAdd(&lh[((u32)ei[N_EDGES + e]) >> BSH], 1u);
    __syncthreads();
    for (int b = t; b < NBUCK; b += 256) {
        u32 c = lh[b];
        lbase[b] = c ? atomicAdd(&gcur[b], c) : 0u;
        lh[b] = 0u;
    }
    __syncthreads();
    for (int e = e0 + t; e < e1; e += 256) {
        u32 d = (u32)ei[N_EDGES + e];
        u32 b = d >> BSH;
        u32 pos = lbase[b] + atomicAdd(&lh[b], 1u);
        pairs[pos] = ((u64)d << 32) | (u32)ei[e];
    }
}

__global__ __launch_bounds__(256) void k_csr(const u64* __restrict__ pairs,
                                             const u32* __restrict__ bbase,
                                             u32* __restrict__ offs,
                                             float* __restrict__ dinv,
                                             u32* __restrict__ ebuf) {
    __shared__ u32 h[512];
    __shared__ u32 sc[512];
    int b = blockIdx.x, t = threadIdx.x;
    u32 lo = (u32)b << BSH;
    u32 base = bbase[b], end = bbase[b + 1];
    for (int i = t; i < 512; i += 256) h[i] = 0u;
    __syncthreads();
    for (u32 i = base + t; i < end; i += 256) {
        u32 dl = (u32)(pairs[i] >> 32) - lo;
        atomicAdd(&h[dl], 1u);
    }
    __syncthreads();
    for (int i = t; i < 512; i += 256) sc[i] = h[i];
    __syncthreads();
    // inclusive scan over 512 entries with 256 threads (read-all then write-all)
    for (int off = 1; off < 512; off <<= 1) {
        int i0 = t, i1 = t + 256;
        u32 v0 = (i0 >= off) ? sc[i0 - off] : 0u;
        u32 v1 = (i1 >= off) ? sc[i1 - off] : 0u;
        __syncthreads();
        sc[i0] += v0; sc[i1] += v1;
        __syncthreads();
    }
    int nn = N_NODES - (int)lo; if (nn > 512) nn = 512;
    for (int i = t; i < nn; i += 256) {
        u32 c = h[i];
        offs[lo + i] = base + (sc[i] - c);
        dinv[lo + i] = rsqrtf((float)c + 1.0f);
    }
    // convert to exclusive prefix = scatter cursors
    for (int i = t; i < 512; i += 256) sc[i] -= h[i];
    __syncthreads();
    for (u32 i = base + t; i < end; i += 256) {
        u64 pr = pairs[i];
        u32 dl = (u32)(pr >> 32) - lo;
        u32 pos = base + atomicAdd(&sc[dl], 1u);
        ebuf[pos] = (u32)pr;
    }
    if (b == 0 && t == 0) offs[N_NODES] = N_EDGES;
}

// ---------------- 5. xw = x @ W_new : bf16 MFMA 16x16x32, fragment-ordered LDS -----

__global__ __launch_bounds__(256) void k_gemm(const float* __restrict__ x,
                                              const u16* __restrict__ Bfrag,
                                              u16* __restrict__ xwh) {
    __shared__ __align__(16) u16 As[8192];    // [rowblk 4][kc 4][lane 64][j 8]
    __shared__ __align__(16) u16 Bs[16384];   // [nb 8][kc 4][lane 64][j 8]
    int t = threadIdx.x;
    int r0 = blockIdx.x * 64;
    #pragma unroll
    for (int i = 0; i < 8; i++) {
        int l = t + i * 256;              // 2048 float4s
        int row = l >> 5, c4 = l & 31;
        int f0 = c4 * 4;
        float4 v = {0.f, 0.f, 0.f, 0.f};
        if (r0 + row < N_NODES) v = *(const float4*)&x[(size_t)(r0 + row) * F + f0];
        int widx = (((row >> 4) * 4 + (f0 >> 5)) * 64 + ((f0 >> 3) & 3) * 16 + (row & 15)) * 8
                   + (f0 & 7);
        ushort4 s4;
        s4.x = f2bf(v.x); s4.y = f2bf(v.y); s4.z = f2bf(v.z); s4.w = f2bf(v.w);
        *(ushort4*)&As[widx] = s4;
    }
    #pragma unroll
    for (int i = 0; i < 8; i++) {
        int idx = t + i * 256;            // 2048 uint4s
        ((uint4*)Bs)[idx] = ((const uint4*)Bfrag)[idx];
    }
    __syncthreads();

    int wv = t >> 6, lane = t & 63;
    floatx4 acc[8] = {};
    #pragma unroll
    for (int kc = 0; kc < 4; kc++) {
        short8 a = *(const short8*)&As[((wv * 4 + kc) * 64 + lane) * 8];
        #pragma unroll
        for (int nb = 0; nb < 8; nb++) {
            short8 b = *(const short8*)&Bs[((nb * 4 + kc) * 64 + lane) * 8];
            acc[nb] = __builtin_amdgcn_mfma_f32_16x16x32_bf16(a, b, acc[nb], 0, 0, 0);
        }
    }
    int q = lane >> 4, m = lane & 15;
    #pragma unroll
    for (int nb = 0; nb < 8; nb++) {
        #pragma unroll
        for (int reg = 0; reg < 4; reg++) {
            int grow = r0 + wv * 16 + q * 4 + reg;
            if (grow < N_NODES)
                xwh[(size_t)grow * F + nb * 16 + m] = f2bf(acc[nb][reg]);
        }
    }
}

// ---------------- 6. gather-aggregate + fused head (bf16 xw, 8-deep MLP) ----------

__global__ void k_gather(const u32* __restrict__ xw32, const u32* __restrict__ offs,
                         const u32* __restrict__ ebuf, const float* __restrict__ dinv,
                         const float* __restrict__ conv_bias, const float* __restrict__ lin_w,
                         const float* __restrict__ lin_b, float* __restrict__ out) {
    int c = blockIdx.x * 4 + (threadIdx.x >> 6);
    if (c >= N_NODES) return;
    int lane = threadIdx.x & 63;
    u32 jbeg = offs[c], jend = offs[c + 1];
    float ax0 = 0.f, ax1 = 0.f, ax2 = 0.f, ax3 = 0.f;
    float ay0 = 0.f, ay1 = 0.f, ay2 = 0.f, ay3 = 0.f;
    u32 j = jbeg;
    for (; j + 8 <= jend; j += 8) {
        u32 r[8], b[8];
        float w[8];
        #pragma unroll
        for (int i = 0; i < 8; i++) r[i] = ebuf[j + i];
        #pragma unroll
        for (int i = 0; i < 8; i++) w[i] = dinv[r[i]];
        #pragma unroll
        for (int i = 0; i < 8; i++) b[i] = xw32[(size_t)r[i] * 64 + lane];
        ax0 += w[0] * __uint_as_float(b[0] << 16); ay0 += w[0] * __uint_as_float(b[0] & 0xffff0000u);
        ax1 += w[1] * __uint_as_float(b[1] << 16); ay1 += w[1] * __uint_as_float(b[1] & 0xffff0000u);
        ax2 += w[2] * __uint_as_float(b[2] << 16); ay2 += w[2] * __uint_as_float(b[2] & 0xffff0000u);
        ax3 += w[3] * __uint_as_float(b[3] << 16); ay3 += w[3] * __uint_as_float(b[3] & 0xffff0000u);
        ax0 += w[4] * __uint_as_float(b[4] << 16); ay0 += w[4] * __uint_as_float(b[4] & 0xffff0000u);
        ax1 += w[5] * __uint_as_float(b[5] << 16); ay1 += w[5] * __uint_as_float(b[5] & 0xffff0000u);
        ax2 += w[6] * __uint_as_float(b[6] << 16); ay2 += w[6] * __uint_as_float(b[6] & 0xffff0000u);
        ax3 += w[7] * __uint_as_float(b[7] << 16); ay3 += w[7] * __uint_as_float(b[7] & 0xffff0000u);
    }
    for (; j < jend; j++) {
        u32 r = ebuf[j];
        float wv = dinv[r];
        u32 b = xw32[(size_t)r * 64 + lane];
        ax0 += wv * __uint_as_float(b << 16);
        ay0 += wv * __uint_as_float(b & 0xffff0000u);
    }
    float accx = (ax0 + ax1) + (ax2 + ax3);
    float accy = (ay0 + ay1) + (ay2 + ay3);
    float dc = dinv[c];
    u32 sbits = xw32[(size_t)c * 64 + lane];
    float slo = __uint_as_float(sbits << 16);
    float shi = __uint_as_float(sbits & 0xffff0000u);
    accx = dc * accx + dc * dc * slo + conv_bias[lane * 2];
    accy = dc * accy + dc * dc * shi + conv_bias[lane * 2 + 1];
    float hx = fmaxf(accx, 0.f), hy = fmaxf(accy, 0.f);
    float part = hx * lin_w[lane * 2] + hy * lin_w[lane * 2 + 1];
    part = wave_reduce(part);
    if (lane == 0) out[c] = part + lin_b[0];
}

// ---------------- launch ----------------

extern "C" void kernel_launch(void* const* d_in, const int* in_sizes, int n_in,
                              void* d_out, int out_size, void* d_ws, size_t ws_size,
                              hipStream_t stream) {
    const float* x         = (const float*)d_in[0];
    const int*   ei        = (const int*)  d_in[1];
    const float* W         = (const float*)d_in[2];
    const float* p         = (const float*)d_in[3];
    const float* w_ih      = (const float*)d_in[4];
    const float* w_hh      = (const float*)d_in[5];
    const float* b_ih      = (const float*)d_in[6];
    const float* b_hh      = (const float*)d_in[7];
    const float* conv_bias = (const float*)d_in[8];
    const float* lin_w     = (const float*)d_in[9];
    const float* lin_b     = (const float*)d_in[10];
    float* out = (float*)d_out;

    u32*   w  = (u32*)d_ws;
    float* wf = (float*)d_ws;

    // ws layout (word offsets), ~46.4 MB total. G (98304 w) overlays PAIRS (dead
    // before k_part).
    const size_t SCORES_W = 0;          // 100000
    const size_t DINV_W   = 100096;     // 100000
    const size_t OFFS_W   = 200192;     // 100001
    const size_t HIST16_W = 300288;     // 65536
    const size_t STATE_W  = 365824;     // 8
    const size_t CAND_W   = 365840;     // 2048
    const size_t TOPI_W   = 367888;     // 128
    const size_t GATE_W   = 368016;     // 128
    const size_t WNEW_W   = 368144;     // 16384
    const size_t BFRAG_W  = 384528;     // 8192
    const size_t BHIST_W  = 392720;     // 256
    const size_t BBASE_W  = 392976;     // 256
    const size_t GCUR_W   = 393232;     // 256
    const size_t PAIRS_W  = 393488;     // u64 x 1600000 = 3200000 words (8B-aligned)
    const size_t EBUF_W   = 3593488;    // 1600000
    const size_t XW_W     = 5193488;    // bf16 xw: 6400000 words

    float* scores  = wf + SCORES_W;
    float* dinv    = wf + DINV_W;
    u32*   offs    = w  + OFFS_W;
    u32*   hist16  = w  + HIST16_W;
    u32*   state   = w  + STATE_W;
    u32*   cand    = w  + CAND_W;
    u32*   top_idx = w  + TOPI_W;
    float* gate    = wf + GATE_W;
    float* Wnew    = wf + WNEW_W;
    u16*   Bfrag   = (u16*)(w + BFRAG_W);
    u32*   bhist   = w  + BHIST_W;
    u32*   bbase   = w  + BBASE_W;
    u32*   gcur    = w  + GCUR_W;
    u64*   pairs   = (u64*)(w + PAIRS_W);
    float* G       = wf + PAIRS_W;      // overlay (dead before k_part)
    u32*   ebuf    = w  + EBUF_W;
    u16*   xwh     = (u16*)(w + XW_W);
    u32*   xw32    = w + XW_W;

    hipMemsetAsync(hist16, 0, (65536 + 8) * sizeof(u32), stream);  // hist16 + state
    hipMemsetAsync(bhist, 0, NBUCK * sizeof(u32), stream);

    // --- top-k + GRU -> W_new (bf16 fragment-packed)
    k_scores<<<25000, 256, 0, stream>>>(x, p, scores, hist16);
    k_scan16<<<1, 1024, 0, stream>>>(hist16, state);
    k_collect16<<<392, 256, 0, stream>>>(scores, state, cand);
    k_assemble16<<<1, 256, 0, stream>>>(scores, p, state, cand, top_idx, gate);
    k_ggemm<<<dim3(4, 12), 256, 0, stream>>>(x, W, w_ih, w_hh, top_idx, gate, G);
    k_gate<<<64, 256, 0, stream>>>(G, W, b_ih, b_hh, Wnew, Bfrag);

    // --- xw = x @ W_new (bf16 MFMA)
    k_gemm<<<1563, 256, 0, stream>>>(x, Bfrag, xwh);

    // --- CSR build (two-level radix)
    k_bhist<<<392, 256, 0, stream>>>(ei, bhist);
    k_bscan<<<1, 256, 0, stream>>>(bhist, bbase, gcur);
    k_part<<<(N_EDGES + PB_EDGES - 1) / PB_EDGES, 256, 0, stream>>>(ei, gcur, pairs);
    k_csr<<<NBUCK, 256, 0, stream>>>(pairs, bbase, offs, dinv, ebuf);

    // --- gather + fused head
    k_gather<<<25000, 256, 0, stream>>>(xw32, offs, ebuf, dinv, conv_bias, lin_w,
                                        lin_b, out);
}

// Round 7
// 345.845 us; speedup vs baseline: 1.8763x; 1.0515x over previous
//
#include <hip/hip_runtime.h>
#include <math.h>

#define N_NODES 100000
#define N_EDGES 1600000
#define F 128

// CSR radix: buckets of 512 destination nodes
#define BSH 9
#define NBUCK 196          // ceil(100000 / 512)
#define PB_EDGES 4096      // edges per k_part block

typedef unsigned int u32;
typedef unsigned short u16;
typedef __attribute__((ext_vector_type(8))) short short8;
typedef __attribute__((ext_vector_type(4))) float floatx4;

// ---------------- helpers ----------------

__device__ __forceinline__ u32 key_of(float s) {
    u32 u = __float_as_uint(s);
    return (u & 0x80000000u) ? ~u : (u | 0x80000000u);   // larger float -> larger key
}

__device__ __forceinline__ float wave_reduce(float v) {
    #pragma unroll
    for (int off = 32; off > 0; off >>= 1) v += __shfl_down(v, off, 64);
    return v;
}

__device__ __forceinline__ u16 f2bf(float f) {   // round-to-nearest-even
    u32 u = __float_as_uint(f);
    u += 0x7fffu + ((u >> 16) & 1u);
    return (u16)(u >> 16);
}

__device__ __forceinline__ float bflo(u32 b) { return __uint_as_float(b << 16); }
__device__ __forceinline__ float bfhi(u32 b) { return __uint_as_float(b & 0xffff0000u); }

// ---------------- 1. scores[i] = x[i] . p  (+ fused 16-bit key histogram) ----------

__global__ void k_scores(const float* __restrict__ x, const float* __restrict__ p,
                         float* __restrict__ scores, u32* __restrict__ hist16) {
    int node = blockIdx.x * 4 + (threadIdx.x >> 6);
    int lane = threadIdx.x & 63;
    if (node >= N_NODES) return;
    float2 xv = *(const float2*)&x[(size_t)node * F + lane * 2];
    float2 pv = *(const float2*)&p[lane * 2];
    float d = xv.x * pv.x + xv.y * pv.y;
    d = wave_reduce(d);
    if (lane == 0) {
        scores[node] = d;
        atomicAdd(&hist16[key_of(d) >> 16], 1u);
    }
}

// ---------------- 2. top-128 select ----------------

__global__ __launch_bounds__(1024) void k_scan16(const u32* __restrict__ hist16,
                                                 u32* __restrict__ state) {
    __shared__ u32 a[1024];
    int t = threadIdx.x;
    const uint4* h4 = (const uint4*)hist16;
    u32 local = 0;
    #pragma unroll
    for (int i = 0; i < 16; i++) {
        uint4 v = h4[t * 16 + i];
        local += v.x + v.y + v.z + v.w;
    }
    a[t] = local;
    __syncthreads();
    for (int off = 1; off < 1024; off <<= 1) {
        u32 add = (t + off < 1024) ? a[t + off] : 0u;
        __syncthreads();
        a[t] += add;
        __syncthreads();
    }
    u32 S_above = (t == 1023) ? 0u : a[t + 1];
    if (S_above < 128u && a[t] >= 128u) {     // threshold bucket is in my chunk
        u32 cum = S_above;
        for (int v = t * 64 + 63; v >= t * 64; v--) {
            cum += hist16[v];
            if (cum >= 128u) { state[0] = (u32)v; break; }
        }
    }
}

__global__ void k_collect16(const float* __restrict__ scores, u32* __restrict__ state,
                            u32* __restrict__ cand) {
    u32 T = state[0] << 16;
    int i = blockIdx.x * blockDim.x + threadIdx.x;
    if (i < N_NODES) {
        if (key_of(scores[i]) >= T) {
            u32 pos = atomicAdd(&state[2], 1u);
            if (pos < 2048u) cand[pos] = (u32)i;
        }
    }
}

__global__ void k_assemble16(const float* __restrict__ scores, const float* __restrict__ p,
                             const u32* __restrict__ state, const u32* __restrict__ cand,
                             u32* __restrict__ top_idx, float* __restrict__ gate) {
    __shared__ u32 ci[2048];
    __shared__ float csc[2048];
    __shared__ float s_inv;
    int t = threadIdx.x;   // 256 threads
    if (t < 64) {
        float2 pv = *(const float2*)&p[t * 2];
        float d = pv.x * pv.x + pv.y * pv.y;
        d = wave_reduce(d);
        if (t == 0) s_inv = rsqrtf(d);
    }
    u32 nc = state[2]; if (nc > 2048u) nc = 2048u;
    for (u32 i = t; i < nc; i += 256) { u32 ix = cand[i]; ci[i] = ix; csc[i] = scores[ix]; }
    __syncthreads();
    for (u32 i = t; i < nc; i += 256) {
        u32 myk = key_of(csc[i]);
        u32 myi = ci[i];
        int rank = 0;
        for (u32 j = 0; j < nc; j++) {
            u32 ok = key_of(csc[j]);
            rank += (int)((ok > myk) || (ok == myk && ci[j] < myi));
        }
        if (rank < 128) {   // exact jax semantics: value desc, index asc on ties
            top_idx[rank] = myi;
            gate[rank] = tanhf(csc[i] * s_inv);
        }
    }
}

// ---------------- 3a. GRU GEMMs: g[128][768] = [x_tilde | W] . [w_ih | w_hh]^T -----

__global__ __launch_bounds__(256) void k_ggemm(const float* __restrict__ x,
                                               const float* __restrict__ W,
                                               const float* __restrict__ w_ih,
                                               const float* __restrict__ w_hh,
                                               const u32* __restrict__ top_idx,
                                               const float* __restrict__ gate,
                                               float* __restrict__ G) {
    __shared__ float As[32][128];
    __shared__ float Bs[64][131];
    int t = threadIdx.x;
    int k0 = blockIdx.x * 32;
    int by = blockIdx.y;                // 0..11; <6 -> gi (w_ih, x_tilde), else gh
    int j0 = by * 64;
    bool is_gi = (by < 6);
    #pragma unroll
    for (int i = 0; i < 4; i++) {
        int l = t + i * 256;
        int row = l >> 5, c4 = l & 31;
        float4 v;
        if (is_gi) {
            u32 idx = top_idx[k0 + row];
            float gt = gate[k0 + row];
            v = *(const float4*)&x[(size_t)idx * F + c4 * 4];
            v.x *= gt; v.y *= gt; v.z *= gt; v.w *= gt;
        } else {
            v = *(const float4*)&W[(k0 + row) * F + c4 * 4];
        }
        *(float4*)&As[row][c4 * 4] = v;
    }
    const float* mat = is_gi ? w_ih : w_hh;
    int jbase = is_gi ? j0 : (j0 - 384);
    #pragma unroll
    for (int i = 0; i < 8; i++) {
        int l = t + i * 256;
        int row = l >> 5, c4 = l & 31;
        float4 v = *(const float4*)&mat[(jbase + row) * F + c4 * 4];
        Bs[row][c4 * 4 + 0] = v.x; Bs[row][c4 * 4 + 1] = v.y;
        Bs[row][c4 * 4 + 2] = v.z; Bs[row][c4 * 4 + 3] = v.w;
    }
    __syncthreads();
    int ty = t >> 5, tx = t & 31;
    float acc[4][2] = {};
    #pragma unroll 4
    for (int f = 0; f < 128; f++) {
        float b0 = Bs[tx * 2][f], b1 = Bs[tx * 2 + 1][f];
        #pragma unroll
        for (int i = 0; i < 4; i++) {
            float a = As[ty * 4 + i][f];
            acc[i][0] += a * b0;
            acc[i][1] += a * b1;
        }
    }
    #pragma unroll
    for (int i = 0; i < 4; i++) {
        int k = k0 + ty * 4 + i;
        G[(size_t)k * 768 + j0 + tx * 2 + 0] = acc[i][0];
        G[(size_t)k * 768 + j0 + tx * 2 + 1] = acc[i][1];
    }
}

// ---------------- 3b. pointwise GRU gates -> Wnew + fragment-ordered bf16 B --------

__global__ void k_gate(const float* __restrict__ G, const float* __restrict__ W,
                       const float* __restrict__ b_ih, const float* __restrict__ b_hh,
                       float* __restrict__ Wnew, u16* __restrict__ Bfrag) {
    int idx = blockIdx.x * blockDim.x + threadIdx.x;   // 16384
    int k = idx >> 7, h = idx & 127;
    const float* gk = &G[(size_t)k * 768];
    float gir = gk[h]       + b_ih[h];
    float giz = gk[128 + h] + b_ih[128 + h];
    float gin = gk[256 + h] + b_ih[256 + h];
    float ghr = gk[384 + h] + b_hh[h];
    float ghz = gk[512 + h] + b_hh[128 + h];
    float ghn = gk[640 + h] + b_hh[256 + h];
    float wv  = W[k * F + h];
    float rg = 1.0f / (1.0f + expf(-(gir + ghr)));
    float z  = 1.0f / (1.0f + expf(-(giz + ghz)));
    float n  = tanhf(gin + rg * ghn);
    float val = (1.0f - z) * n + z * wv;
    Wnew[k * F + h] = val;
    int nb = h >> 4, kc = k >> 5, q = (k >> 3) & 3, m = h & 15, jj = k & 7;
    Bfrag[(((nb * 4 + kc) * 64) + q * 16 + m) * 8 + jj] = f2bf(val);
}

// ---------------- 4. CSR build: two-level radix scatter (u32-packed pairs) ---------
// pack = dst_local(9b) << 17 | src(17b); bucket implied by pairs segment.

__global__ void k_bhist(const int* __restrict__ ei, u32* __restrict__ bhist) {
    __shared__ u32 h[NBUCK];
    int t = threadIdx.x;
    for (int i = t; i < NBUCK; i += 256) h[i] = 0u;
    __syncthreads();
    for (int e = blockIdx.x * blockDim.x + t; e < N_EDGES; e += gridDim.x * blockDim.x)
        atomicAdd(&h[((u32)ei[N_EDGES + e]) >> BSH], 1u);
    __syncthreads();
    for (int i = t; i < NBUCK; i += 256) if (h[i]) atomicAdd(&bhist[i], h[i]);
}

__global__ void k_bscan(const u32* __restrict__ bhist, u32* __restrict__ bbase,
                        u32* __restrict__ gcur) {
    __shared__ u32 s[256];
    int t = threadIdx.x;
    u32 v = (t < NBUCK) ? bhist[t] : 0u;
    s[t] = v;
    __syncthreads();
    for (int off = 1; off < 256; off <<= 1) {
        u32 add = (t >= off) ? s[t - off] : 0u;
        __syncthreads();
        s[t] += add;
        __syncthreads();
    }
    u32 excl = s[t] - v;
    if (t < NBUCK) { bbase[t] = excl; gcur[t] = excl; }
    if (t == 0) bbase[NBUCK] = N_EDGES;
}

__global__ void k_part(const int* __restrict__ ei, u32* __restrict__ gcur,
                       u32* __restrict__ pairs) {
    __shared__ u32 lh[NBUCK];     // local histogram, then local cursor
    __shared__ u32 lbase[NBUCK];  // reserved global base per bucket
    int t = threadIdx.x;
    int e0 = blockIdx.x * PB_EDGES;
    int e1 = e0 + PB_EDGES; if (e1 > N_EDGES) e1 = N_EDGES;
    for (int i = t; i < NBUCK; i += 256) lh[i] = 0u;
    __syncthreads();
    for (int e = e0 + t; e < e1; e += 256)
        atomicAdd(&lh[((u32)ei[N_EDGES + e]) >> BSH], 1u);
    __syncthreads();
    for (int b = t; b < NBUCK; b += 256) {
        u32 c = lh[b];
        lbase[b] = c ? atomicAdd(&gcur[b], c) : 0u;
        lh[b] = 0u;
    }
    __syncthreads();
    for (int e = e0 + t; e < e1; e += 256) {
        u32 d = (u32)ei[N_EDGES + e];
        u32 b = d >> BSH;
        u32 pos = lbase[b] + atomicAdd(&lh[b], 1u);
        pairs[pos] = ((d & 511u) << 17) | (u32)ei[e];
    }
}

__global__ __launch_bounds__(256) void k_csr(const u32* __restrict__ pairs,
                                             const u32* __restrict__ bbase,
                                             u32* __restrict__ offs,
                                             float* __restrict__ dinv,
                                             u32* __restrict__ ebuf) {
    __shared__ u32 h[512];
    __shared__ u32 sc[512];
    int b = blockIdx.x, t = threadIdx.x;
    u32 lo = (u32)b << BSH;
    u32 base = bbase[b], end = bbase[b + 1];
    for (int i = t; i < 512; i += 256) h[i] = 0u;
    __syncthreads();
    for (u32 i = base + t; i < end; i += 256)
        atomicAdd(&h[pairs[i] >> 17], 1u);
    __syncthreads();
    for (int i = t; i < 512; i += 256) sc[i] = h[i];
    __syncthreads();
    // inclusive scan over 512 entries with 256 threads
    for (int off = 1; off < 512; off <<= 1) {
        int i0 = t, i1 = t + 256;
        u32 v0 = (i0 >= off) ? sc[i0 - off] : 0u;
        u32 v1 = (i1 >= off) ? sc[i1 - off] : 0u;
        __syncthreads();
        sc[i0] += v0; sc[i1] += v1;
        __syncthreads();
    }
    int nn = N_NODES - (int)lo; if (nn > 512) nn = 512;
    for (int i = t; i < nn; i += 256) {
        u32 c = h[i];
        offs[lo + i] = base + (sc[i] - c);
        dinv[lo + i] = rsqrtf((float)c + 1.0f);
    }
    // convert to exclusive prefix = scatter cursors
    for (int i = t; i < 512; i += 256) sc[i] -= h[i];
    __syncthreads();
    for (u32 i = base + t; i < end; i += 256) {
        u32 pr = pairs[i];
        u32 pos = base + atomicAdd(&sc[pr >> 17], 1u);
        ebuf[pos] = pr & 0x1ffffu;
    }
    if (b == 0 && t == 0) offs[N_NODES] = N_EDGES;
}

// ---------------- 5. xw = x @ W_new : bf16 MFMA 16x16x32, fragment-ordered LDS -----

__global__ __launch_bounds__(256) void k_gemm(const float* __restrict__ x,
                                              const u16* __restrict__ Bfrag,
                                              u16* __restrict__ xwh) {
    __shared__ __align__(16) u16 As[8192];    // [rowblk 4][kc 4][lane 64][j 8]
    __shared__ __align__(16) u16 Bs[16384];   // [nb 8][kc 4][lane 64][j 8]
    int t = threadIdx.x;
    int r0 = blockIdx.x * 64;
    #pragma unroll
    for (int i = 0; i < 8; i++) {
        int l = t + i * 256;              // 2048 float4s
        int row = l >> 5, c4 = l & 31;
        int f0 = c4 * 4;
        float4 v = {0.f, 0.f, 0.f, 0.f};
        if (r0 + row < N_NODES) v = *(const float4*)&x[(size_t)(r0 + row) * F + f0];
        int widx = (((row >> 4) * 4 + (f0 >> 5)) * 64 + ((f0 >> 3) & 3) * 16 + (row & 15)) * 8
                   + (f0 & 7);
        ushort4 s4;
        s4.x = f2bf(v.x); s4.y = f2bf(v.y); s4.z = f2bf(v.z); s4.w = f2bf(v.w);
        *(ushort4*)&As[widx] = s4;
    }
    #pragma unroll
    for (int i = 0; i < 8; i++) {
        int idx = t + i * 256;            // 2048 uint4s
        ((uint4*)Bs)[idx] = ((const uint4*)Bfrag)[idx];
    }
    __syncthreads();

    int wv = t >> 6, lane = t & 63;
    floatx4 acc[8] = {};
    #pragma unroll
    for (int kc = 0; kc < 4; kc++) {
        short8 a = *(const short8*)&As[((wv * 4 + kc) * 64 + lane) * 8];
        #pragma unroll
        for (int nb = 0; nb < 8; nb++) {
            short8 b = *(const short8*)&Bs[((nb * 4 + kc) * 64 + lane) * 8];
            acc[nb] = __builtin_amdgcn_mfma_f32_16x16x32_bf16(a, b, acc[nb], 0, 0, 0);
        }
    }
    int q = lane >> 4, m = lane & 15;
    #pragma unroll
    for (int nb = 0; nb < 8; nb++) {
        #pragma unroll
        for (int reg = 0; reg < 4; reg++) {
            int grow = r0 + wv * 16 + q * 4 + reg;
            if (grow < N_NODES)
                xwh[(size_t)grow * F + nb * 16 + m] = f2bf(acc[nb][reg]);
        }
    }
}

// ---------------- 6. gather-aggregate + fused head --------------------------------
// One wave per node; lanes 0-31 = edge a, lanes 32-63 = edge b (2 edges/instruction,
// uint2 = 4 bf16 per lane). Cross-half combine via shfl_xor(32); fused epilogue.

__global__ void k_gather(const u32* __restrict__ xw32, const u32* __restrict__ offs,
                         const u32* __restrict__ ebuf, const float* __restrict__ dinv,
                         const float* __restrict__ conv_bias, const float* __restrict__ lin_w,
                         const float* __restrict__ lin_b, float* __restrict__ out) {
    int c = blockIdx.x * 4 + (threadIdx.x >> 6);
    if (c >= N_NODES) return;
    int lane = threadIdx.x & 63;
    int half = lane >> 5, sub = lane & 31;
    u32 jbeg = offs[c], jend = offs[c + 1];
    float ax = 0.f, ay = 0.f, az = 0.f, aw = 0.f;
    u32 j = jbeg;
    for (; j + 8 <= jend; j += 8) {          // 8 edges (4 pairs) in flight
        u32 r0 = ebuf[j + 0 + half];
        u32 r1 = ebuf[j + 2 + half];
        u32 r2 = ebuf[j + 4 + half];
        u32 r3 = ebuf[j + 6 + half];
        float w0 = dinv[r0], w1 = dinv[r1], w2 = dinv[r2], w3 = dinv[r3];
        uint2 b0 = *(const uint2*)&xw32[(size_t)r0 * 64 + sub * 2];
        uint2 b1 = *(const uint2*)&xw32[(size_t)r1 * 64 + sub * 2];
        uint2 b2 = *(const uint2*)&xw32[(size_t)r2 * 64 + sub * 2];
        uint2 b3 = *(const uint2*)&xw32[(size_t)r3 * 64 + sub * 2];
        ax += w0 * bflo(b0.x); ay += w0 * bfhi(b0.x); az += w0 * bflo(b0.y); aw += w0 * bfhi(b0.y);
        ax += w1 * bflo(b1.x); ay += w1 * bfhi(b1.x); az += w1 * bflo(b1.y); aw += w1 * bfhi(b1.y);
        ax += w2 * bflo(b2.x); ay += w2 * bfhi(b2.x); az += w2 * bflo(b2.y); aw += w2 * bfhi(b2.y);
        ax += w3 * bflo(b3.x); ay += w3 * bfhi(b3.x); az += w3 * bflo(b3.y); aw += w3 * bfhi(b3.y);
    }
    for (; j + 2 <= jend; j += 2) {          // single pair
        u32 r = ebuf[j + half];
        float wv = dinv[r];
        uint2 b = *(const uint2*)&xw32[(size_t)r * 64 + sub * 2];
        ax += wv * bflo(b.x); ay += wv * bfhi(b.x); az += wv * bflo(b.y); aw += wv * bfhi(b.y);
    }
    if (j < jend) {                          // odd tail: half 1 contributes zero
        u32 r = ebuf[j];
        float wv = half ? 0.f : dinv[r];
        uint2 b = *(const uint2*)&xw32[(size_t)r * 64 + sub * 2];
        ax += wv * bflo(b.x); ay += wv * bfhi(b.x); az += wv * bflo(b.y); aw += wv * bfhi(b.y);
    }
    ax += __shfl_xor(ax, 32, 64);
    ay += __shfl_xor(ay, 32, 64);
    az += __shfl_xor(az, 32, 64);
    aw += __shfl_xor(aw, 32, 64);
    float dc = dinv[c], d2 = dc * dc;
    uint2 sb = *(const uint2*)&xw32[(size_t)c * 64 + sub * 2];
    float4 cb = *(const float4*)&conv_bias[sub * 4];
    float4 lw = *(const float4*)&lin_w[sub * 4];
    float h0 = fmaxf(dc * ax + d2 * bflo(sb.x) + cb.x, 0.f);
    float h1 = fmaxf(dc * ay + d2 * bfhi(sb.x) + cb.y, 0.f);
    float h2 = fmaxf(dc * az + d2 * bflo(sb.y) + cb.z, 0.f);
    float h3 = fmaxf(dc * aw + d2 * bfhi(sb.y) + cb.w, 0.f);
    float part = h0 * lw.x + h1 * lw.y + h2 * lw.z + h3 * lw.w;
    part = half ? 0.f : part;
    part = wave_reduce(part);
    if (lane == 0) out[c] = part + lin_b[0];
}

// ---------------- launch ----------------

extern "C" void kernel_launch(void* const* d_in, const int* in_sizes, int n_in,
                              void* d_out, int out_size, void* d_ws, size_t ws_size,
                              hipStream_t stream) {
    const float* x         = (const float*)d_in[0];
    const int*   ei        = (const int*)  d_in[1];
    const float* W         = (const float*)d_in[2];
    const float* p         = (const float*)d_in[3];
    const float* w_ih      = (const float*)d_in[4];
    const float* w_hh      = (const float*)d_in[5];
    const float* b_ih      = (const float*)d_in[6];
    const float* b_hh      = (const float*)d_in[7];
    const float* conv_bias = (const float*)d_in[8];
    const float* lin_w     = (const float*)d_in[9];
    const float* lin_b     = (const float*)d_in[10];
    float* out = (float*)d_out;

    u32*   w  = (u32*)d_ws;
    float* wf = (float*)d_ws;

    // ws layout (word offsets), ~40 MB total. G (98304 w) overlays PAIRS (dead
    // before k_part). hist16/state/bhist contiguous -> ONE memset.
    const size_t SCORES_W = 0;          // 100000
    const size_t DINV_W   = 100096;     // 100000
    const size_t OFFS_W   = 200192;     // 100001
    const size_t HIST16_W = 300288;     // 65536
    const size_t STATE_W  = 365824;     // 8
    const size_t BHIST_W  = 365832;     // 196 (memset covers hist16..bhist)
    const size_t CAND_W   = 366080;     // 2048
    const size_t TOPI_W   = 368128;     // 128
    const size_t GATE_W   = 368256;     // 128
    const size_t WNEW_W   = 368384;     // 16384
    const size_t BFRAG_W  = 384768;     // 8192
    const size_t BBASE_W  = 392960;     // 256
    const size_t GCUR_W   = 393216;     // 256
    const size_t PAIRS_W  = 393472;     // u32 x 1600000
    const size_t EBUF_W   = 1993472;    // 1600000
    const size_t XW_W     = 3593472;    // bf16 xw: 6400000 words

    float* scores  = wf + SCORES_W;
    float* dinv    = wf + DINV_W;
    u32*   offs    = w  + OFFS_W;
    u32*   hist16  = w  + HIST16_W;
    u32*   state   = w  + STATE_W;
    u32*   bhist   = w  + BHIST_W;
    u32*   cand    = w  + CAND_W;
    u32*   top_idx = w  + TOPI_W;
    float* gate    = wf + GATE_W;
    float* Wnew    = wf + WNEW_W;
    u16*   Bfrag   = (u16*)(w + BFRAG_W);
    u32*   bbase   = w  + BBASE_W;
    u32*   gcur    = w  + GCUR_W;
    u32*   pairs   = w  + PAIRS_W;
    float* G       = wf + PAIRS_W;      // overlay (dead before k_part)
    u32*   ebuf    = w  + EBUF_W;
    u16*   xwh     = (u16*)(w + XW_W);
    u32*   xw32    = w + XW_W;

    hipMemsetAsync(hist16, 0, (65536 + 8 + NBUCK) * sizeof(u32), stream);

    // --- top-k + GRU -> W_new (bf16 fragment-packed)
    k_scores<<<25000, 256, 0, stream>>>(x, p, scores, hist16);
    k_scan16<<<1, 1024, 0, stream>>>(hist16, state);
    k_collect16<<<392, 256, 0, stream>>>(scores, state, cand);
    k_assemble16<<<1, 256, 0, stream>>>(scores, p, state, cand, top_idx, gate);
    k_ggemm<<<dim3(4, 12), 256, 0, stream>>>(x, W, w_ih, w_hh, top_idx, gate, G);
    k_gate<<<64, 256, 0, stream>>>(G, W, b_ih, b_hh, Wnew, Bfrag);

    // --- xw = x @ W_new (bf16 MFMA)
    k_gemm<<<1563, 256, 0, stream>>>(x, Bfrag, xwh);

    // --- CSR build (two-level radix, u32-packed)
    k_bhist<<<392, 256, 0, stream>>>(ei, bhist);
    k_bscan<<<1, 256, 0, stream>>>(bhist, bbase, gcur);
    k_part<<<(N_EDGES + PB_EDGES - 1) / PB_EDGES, 256, 0, stream>>>(ei, gcur, pairs);
    k_csr<<<NBUCK, 256, 0, stream>>>(pairs, bbase, offs, dinv, ebuf);

    // --- gather + fused head
    k_gather<<<25000, 256, 0, stream>>>(xw32, offs, ebuf, dinv, conv_bias, lin_w,
                                        lin_b, out);
}

// Round 8
// 330.623 us; speedup vs baseline: 1.9627x; 1.0460x over previous
//
#include <hip/hip_runtime.h>
#include <math.h>

#define N_NODES 100000
#define N_EDGES 1600000
#define F 128

// CSR radix: buckets of 512 destination nodes, fixed-capacity segments
#define BSH 9
#define NBUCK 196          // ceil(100000 / 512)
#define BCAP 10240         // per-bucket capacity (mean 8163, +22 sigma)
#define PB_EDGES 4096      // edges per k_part block

typedef unsigned int u32;
typedef unsigned short u16;
typedef __attribute__((ext_vector_type(8))) short short8;
typedef __attribute__((ext_vector_type(4))) float floatx4;

// ---------------- helpers ----------------

__device__ __forceinline__ u32 key_of(float s) {
    u32 u = __float_as_uint(s);
    return (u & 0x80000000u) ? ~u : (u | 0x80000000u);   // larger float -> larger key
}

__device__ __forceinline__ float wave_reduce(float v) {
    #pragma unroll
    for (int off = 32; off > 0; off >>= 1) v += __shfl_down(v, off, 64);
    return v;
}

__device__ __forceinline__ u16 f2bf(float f) {   // round-to-nearest-even
    u32 u = __float_as_uint(f);
    u += 0x7fffu + ((u >> 16) & 1u);
    return (u16)(u >> 16);
}

__device__ __forceinline__ float bflo(u32 b) { return __uint_as_float(b << 16); }
__device__ __forceinline__ float bfhi(u32 b) { return __uint_as_float(b & 0xffff0000u); }

// ---------------- 1. scores[i] = x[i] . p  (+ fused 16-bit key histogram) ----------

__global__ void k_scores(const float* __restrict__ x, const float* __restrict__ p,
                         float* __restrict__ scores, u32* __restrict__ hist16) {
    int node = blockIdx.x * 4 + (threadIdx.x >> 6);
    int lane = threadIdx.x & 63;
    if (node >= N_NODES) return;
    float2 xv = *(const float2*)&x[(size_t)node * F + lane * 2];
    float2 pv = *(const float2*)&p[lane * 2];
    float d = xv.x * pv.x + xv.y * pv.y;
    d = wave_reduce(d);
    if (lane == 0) {
        scores[node] = d;
        atomicAdd(&hist16[key_of(d) >> 16], 1u);
    }
}

// ---------------- 2. top-128 select ----------------

__global__ __launch_bounds__(1024) void k_scan16(const u32* __restrict__ hist16,
                                                 u32* __restrict__ state) {
    __shared__ u32 a[1024];
    int t = threadIdx.x;
    const uint4* h4 = (const uint4*)hist16;
    u32 local = 0;
    #pragma unroll
    for (int i = 0; i < 16; i++) {
        uint4 v = h4[t * 16 + i];
        local += v.x + v.y + v.z + v.w;
    }
    a[t] = local;
    __syncthreads();
    for (int off = 1; off < 1024; off <<= 1) {
        u32 add = (t + off < 1024) ? a[t + off] : 0u;
        __syncthreads();
        a[t] += add;
        __syncthreads();
    }
    u32 S_above = (t == 1023) ? 0u : a[t + 1];
    if (S_above < 128u && a[t] >= 128u) {     // threshold bucket is in my chunk
        u32 cum = S_above;
        for (int v = t * 64 + 63; v >= t * 64; v--) {
            cum += hist16[v];
            if (cum >= 128u) { state[0] = (u32)v; break; }
        }
    }
}

__global__ void k_collect16(const float* __restrict__ scores, u32* __restrict__ state,
                            u32* __restrict__ cand) {
    u32 T = state[0] << 16;
    int i = blockIdx.x * blockDim.x + threadIdx.x;
    if (i < N_NODES) {
        if (key_of(scores[i]) >= T) {
            u32 pos = atomicAdd(&state[2], 1u);
            if (pos < 2048u) cand[pos] = (u32)i;
        }
    }
}

__global__ void k_assemble16(const float* __restrict__ scores, const float* __restrict__ p,
                             const u32* __restrict__ state, const u32* __restrict__ cand,
                             u32* __restrict__ top_idx, float* __restrict__ gate) {
    __shared__ u32 ci[2048];
    __shared__ float csc[2048];
    __shared__ float s_inv;
    int t = threadIdx.x;   // 256 threads
    if (t < 64) {
        float2 pv = *(const float2*)&p[t * 2];
        float d = pv.x * pv.x + pv.y * pv.y;
        d = wave_reduce(d);
        if (t == 0) s_inv = rsqrtf(d);
    }
    u32 nc = state[2]; if (nc > 2048u) nc = 2048u;
    for (u32 i = t; i < nc; i += 256) { u32 ix = cand[i]; ci[i] = ix; csc[i] = scores[ix]; }
    __syncthreads();
    for (u32 i = t; i < nc; i += 256) {
        u32 myk = key_of(csc[i]);
        u32 myi = ci[i];
        int rank = 0;
        for (u32 j = 0; j < nc; j++) {
            u32 ok = key_of(csc[j]);
            rank += (int)((ok > myk) || (ok == myk && ci[j] < myi));
        }
        if (rank < 128) {   // exact jax semantics: value desc, index asc on ties
            top_idx[rank] = myi;
            gate[rank] = tanhf(csc[i] * s_inv);
        }
    }
}

// ---------------- 3a. GRU GEMMs: g[128][768] = [x_tilde | W] . [w_ih | w_hh]^T -----

__global__ __launch_bounds__(256) void k_ggemm(const float* __restrict__ x,
                                               const float* __restrict__ W,
                                               const float* __restrict__ w_ih,
                                               const float* __restrict__ w_hh,
                                               const u32* __restrict__ top_idx,
                                               const float* __restrict__ gate,
                                               float* __restrict__ G) {
    __shared__ float As[32][128];
    __shared__ float Bs[64][131];
    int t = threadIdx.x;
    int k0 = blockIdx.x * 32;
    int by = blockIdx.y;                // 0..11; <6 -> gi (w_ih, x_tilde), else gh
    int j0 = by * 64;
    bool is_gi = (by < 6);
    #pragma unroll
    for (int i = 0; i < 4; i++) {
        int l = t + i * 256;
        int row = l >> 5, c4 = l & 31;
        float4 v;
        if (is_gi) {
            u32 idx = top_idx[k0 + row];
            float gt = gate[k0 + row];
            v = *(const float4*)&x[(size_t)idx * F + c4 * 4];
            v.x *= gt; v.y *= gt; v.z *= gt; v.w *= gt;
        } else {
            v = *(const float4*)&W[(k0 + row) * F + c4 * 4];
        }
        *(float4*)&As[row][c4 * 4] = v;
    }
    const float* mat = is_gi ? w_ih : w_hh;
    int jbase = is_gi ? j0 : (j0 - 384);
    #pragma unroll
    for (int i = 0; i < 8; i++) {
        int l = t + i * 256;
        int row = l >> 5, c4 = l & 31;
        float4 v = *(const float4*)&mat[(jbase + row) * F + c4 * 4];
        Bs[row][c4 * 4 + 0] = v.x; Bs[row][c4 * 4 + 1] = v.y;
        Bs[row][c4 * 4 + 2] = v.z; Bs[row][c4 * 4 + 3] = v.w;
    }
    __syncthreads();
    int ty = t >> 5, tx = t & 31;
    float acc[4][2] = {};
    #pragma unroll 4
    for (int f = 0; f < 128; f++) {
        float b0 = Bs[tx * 2][f], b1 = Bs[tx * 2 + 1][f];
        #pragma unroll
        for (int i = 0; i < 4; i++) {
            float a = As[ty * 4 + i][f];
            acc[i][0] += a * b0;
            acc[i][1] += a * b1;
        }
    }
    #pragma unroll
    for (int i = 0; i < 4; i++) {
        int k = k0 + ty * 4 + i;
        G[(size_t)k * 768 + j0 + tx * 2 + 0] = acc[i][0];
        G[(size_t)k * 768 + j0 + tx * 2 + 1] = acc[i][1];
    }
}

// ---------------- 3b. pointwise GRU gates -> Wnew + fragment-ordered bf16 B --------

__global__ void k_gate(const float* __restrict__ G, const float* __restrict__ W,
                       const float* __restrict__ b_ih, const float* __restrict__ b_hh,
                       float* __restrict__ Wnew, u16* __restrict__ Bfrag) {
    int idx = blockIdx.x * blockDim.x + threadIdx.x;   // 16384
    int k = idx >> 7, h = idx & 127;
    const float* gk = &G[(size_t)k * 768];
    float gir = gk[h]       + b_ih[h];
    float giz = gk[128 + h] + b_ih[128 + h];
    float gin = gk[256 + h] + b_ih[256 + h];
    float ghr = gk[384 + h] + b_hh[h];
    float ghz = gk[512 + h] + b_hh[128 + h];
    float ghn = gk[640 + h] + b_hh[256 + h];
    float wv  = W[k * F + h];
    float rg = 1.0f / (1.0f + expf(-(gir + ghr)));
    float z  = 1.0f / (1.0f + expf(-(giz + ghz)));
    float n  = tanhf(gin + rg * ghn);
    float val = (1.0f - z) * n + z * wv;
    Wnew[k * F + h] = val;
    int nb = h >> 4, kc = k >> 5, q = (k >> 3) & 3, m = h & 15, jj = k & 7;
    Bfrag[(((nb * 4 + kc) * 64) + q * 16 + m) * 8 + jj] = f2bf(val);
}

// ---------------- 4. CSR build: fixed-capacity radix scatter -----------------------
// pack = dst_local(9b) << 17 | src(17b); bucket b owns pairs[b*BCAP .. b*BCAP+cnt).

__global__ void k_part(const int* __restrict__ ei, u32* __restrict__ gcur,
                       u32* __restrict__ pairs) {
    __shared__ u32 lh[NBUCK];     // local histogram, then local cursor
    __shared__ u32 lbase[NBUCK];  // reserved base within bucket segment
    int t = threadIdx.x;
    int e0 = blockIdx.x * PB_EDGES;
    int e1 = e0 + PB_EDGES; if (e1 > N_EDGES) e1 = N_EDGES;
    for (int i = t; i < NBUCK; i += 256) lh[i] = 0u;
    __syncthreads();
    for (int e = e0 + t; e < e1; e += 256)
        atomicAdd(&lh[((u32)ei[N_EDGES + e]) >> BSH], 1u);
    __syncthreads();
    for (int b = t; b < NBUCK; b += 256) {
        u32 c = lh[b];
        lbase[b] = c ? atomicAdd(&gcur[b], c) : 0u;
        lh[b] = 0u;
    }
    __syncthreads();
    for (int e = e0 + t; e < e1; e += 256) {
        u32 d = (u32)ei[N_EDGES + e];
        u32 b = d >> BSH;
        u32 pos = lbase[b] + atomicAdd(&lh[b], 1u);
        pairs[(size_t)b * BCAP + pos] = ((d & 511u) << 17) | (u32)ei[e];
    }
}

__global__ __launch_bounds__(256) void k_csr(const u32* __restrict__ pairs,
                                             const u32* __restrict__ gcur,
                                             u32* __restrict__ offs,
                                             float* __restrict__ dinv,
                                             u32* __restrict__ ebuf) {
    __shared__ u32 h[512];
    __shared__ u32 sc[512];
    __shared__ u32 ps[256];
    int b = blockIdx.x, t = threadIdx.x;
    // per-block recompute of the 196-bucket prefix (reads 196 u32 from L2)
    u32 pv = (t < NBUCK) ? gcur[t] : 0u;
    ps[t] = pv;
    __syncthreads();
    for (int off = 1; off < 256; off <<= 1) {
        u32 add = (t >= off) ? ps[t - off] : 0u;
        __syncthreads();
        ps[t] += add;
        __syncthreads();
    }
    u32 base = ps[b] - gcur[b];
    u32 cnt  = gcur[b];
    const u32* seg = pairs + (size_t)b * BCAP;
    u32 lo = (u32)b << BSH;
    for (int i = t; i < 512; i += 256) h[i] = 0u;
    __syncthreads();
    for (u32 i = t; i < cnt; i += 256)
        atomicAdd(&h[seg[i] >> 17], 1u);
    __syncthreads();
    for (int i = t; i < 512; i += 256) sc[i] = h[i];
    __syncthreads();
    // inclusive scan over 512 entries with 256 threads
    for (int off = 1; off < 512; off <<= 1) {
        int i0 = t, i1 = t + 256;
        u32 v0 = (i0 >= off) ? sc[i0 - off] : 0u;
        u32 v1 = (i1 >= off) ? sc[i1 - off] : 0u;
        __syncthreads();
        sc[i0] += v0; sc[i1] += v1;
        __syncthreads();
    }
    int nn = N_NODES - (int)lo; if (nn > 512) nn = 512;
    for (int i = t; i < nn; i += 256) {
        u32 c = h[i];
        offs[lo + i] = base + (sc[i] - c);
        dinv[lo + i] = rsqrtf((float)c + 1.0f);
    }
    // convert to exclusive prefix = scatter cursors
    for (int i = t; i < 512; i += 256) sc[i] -= h[i];
    __syncthreads();
    for (u32 i = t; i < cnt; i += 256) {
        u32 pr = seg[i];
        u32 pos = base + atomicAdd(&sc[pr >> 17], 1u);
        ebuf[pos] = pr & 0x1ffffu;
    }
    if (b == 0 && t == 0) offs[N_NODES] = N_EDGES;
}

// ---------------- 5. xw = x @ W_new : bf16 MFMA 16x16x32, fragment-ordered LDS -----

__global__ __launch_bounds__(256) void k_gemm(const float* __restrict__ x,
                                              const u16* __restrict__ Bfrag,
                                              u16* __restrict__ xwh) {
    __shared__ __align__(16) u16 As[8192];    // [rowblk 4][kc 4][lane 64][j 8]
    __shared__ __align__(16) u16 Bs[16384];   // [nb 8][kc 4][lane 64][j 8]
    int t = threadIdx.x;
    int r0 = blockIdx.x * 64;
    #pragma unroll
    for (int i = 0; i < 8; i++) {
        int l = t + i * 256;              // 2048 float4s
        int row = l >> 5, c4 = l & 31;
        int f0 = c4 * 4;
        float4 v = {0.f, 0.f, 0.f, 0.f};
        if (r0 + row < N_NODES) v = *(const float4*)&x[(size_t)(r0 + row) * F + f0];
        int widx = (((row >> 4) * 4 + (f0 >> 5)) * 64 + ((f0 >> 3) & 3) * 16 + (row & 15)) * 8
                   + (f0 & 7);
        ushort4 s4;
        s4.x = f2bf(v.x); s4.y = f2bf(v.y); s4.z = f2bf(v.z); s4.w = f2bf(v.w);
        *(ushort4*)&As[widx] = s4;
    }
    #pragma unroll
    for (int i = 0; i < 8; i++) {
        int idx = t + i * 256;            // 2048 uint4s
        ((uint4*)Bs)[idx] = ((const uint4*)Bfrag)[idx];
    }
    __syncthreads();

    int wv = t >> 6, lane = t & 63;
    floatx4 acc[8] = {};
    #pragma unroll
    for (int kc = 0; kc < 4; kc++) {
        short8 a = *(const short8*)&As[((wv * 4 + kc) * 64 + lane) * 8];
        #pragma unroll
        for (int nb = 0; nb < 8; nb++) {
            short8 b = *(const short8*)&Bs[((nb * 4 + kc) * 64 + lane) * 8];
            acc[nb] = __builtin_amdgcn_mfma_f32_16x16x32_bf16(a, b, acc[nb], 0, 0, 0);
        }
    }
    int q = lane >> 4, m = lane & 15;
    #pragma unroll
    for (int nb = 0; nb < 8; nb++) {
        #pragma unroll
        for (int reg = 0; reg < 4; reg++) {
            int grow = r0 + wv * 16 + q * 4 + reg;
            if (grow < N_NODES)
                xwh[(size_t)grow * F + nb * 16 + m] = f2bf(acc[nb][reg]);
        }
    }
}

// ---------------- 6. gather-aggregate + fused head --------------------------------
// One wave per node; quarter-wave per edge (4 edges/instruction, uint4 = 8 bf16 per
// lane). Cross-quarter combine via shfl_xor(16/32); fused epilogue.

#define EDGE_GROUP(J) {                                                      \
    u32 r = ebuf[(J) + q];                                                   \
    float wv = dinv[r];                                                      \
    uint4 bb = *(const uint4*)&xw32[(size_t)r * 64 + sub * 4];               \
    a0 += wv * bflo(bb.x); a1 += wv * bfhi(bb.x);                            \
    a2 += wv * bflo(bb.y); a3 += wv * bfhi(bb.y);                            \
    a4 += wv * bflo(bb.z); a5 += wv * bfhi(bb.z);                            \
    a6 += wv * bflo(bb.w); a7 += wv * bfhi(bb.w); }

__global__ void k_gather(const u32* __restrict__ xw32, const u32* __restrict__ offs,
                         const u32* __restrict__ ebuf, const float* __restrict__ dinv,
                         const float* __restrict__ conv_bias, const float* __restrict__ lin_w,
                         const float* __restrict__ lin_b, float* __restrict__ out) {
    int c = blockIdx.x * 4 + (threadIdx.x >> 6);
    if (c >= N_NODES) return;
    int lane = threadIdx.x & 63;
    int q = lane >> 4, sub = lane & 15;
    u32 jbeg = offs[c], jend = offs[c + 1];
    float a0 = 0.f, a1 = 0.f, a2 = 0.f, a3 = 0.f;
    float a4 = 0.f, a5 = 0.f, a6 = 0.f, a7 = 0.f;
    u32 j = jbeg;
    for (; j + 16 <= jend; j += 16) {   // 16 edges (4 quad-groups) in flight
        EDGE_GROUP(j) EDGE_GROUP(j + 4) EDGE_GROUP(j + 8) EDGE_GROUP(j + 12)
    }
    for (; j + 4 <= jend; j += 4) EDGE_GROUP(j)
    u32 rem = jend - j;
    if (rem) {                           // 1..3 leftover edges
        u32 idx = ((u32)q < rem) ? (j + q) : (jend - 1);
        u32 r = ebuf[idx];
        float wv = ((u32)q < rem) ? dinv[r] : 0.f;
        uint4 bb = *(const uint4*)&xw32[(size_t)r * 64 + sub * 4];
        a0 += wv * bflo(bb.x); a1 += wv * bfhi(bb.x);
        a2 += wv * bflo(bb.y); a3 += wv * bfhi(bb.y);
        a4 += wv * bflo(bb.z); a5 += wv * bfhi(bb.z);
        a6 += wv * bflo(bb.w); a7 += wv * bfhi(bb.w);
    }
    // combine quarters: butterfly over lane^16, lane^32
    a0 += __shfl_xor(a0, 16, 64); a0 += __shfl_xor(a0, 32, 64);
    a1 += __shfl_xor(a1, 16, 64); a1 += __shfl_xor(a1, 32, 64);
    a2 += __shfl_xor(a2, 16, 64); a2 += __shfl_xor(a2, 32, 64);
    a3 += __shfl_xor(a3, 16, 64); a3 += __shfl_xor(a3, 32, 64);
    a4 += __shfl_xor(a4, 16, 64); a4 += __shfl_xor(a4, 32, 64);
    a5 += __shfl_xor(a5, 16, 64); a5 += __shfl_xor(a5, 32, 64);
    a6 += __shfl_xor(a6, 16, 64); a6 += __shfl_xor(a6, 32, 64);
    a7 += __shfl_xor(a7, 16, 64); a7 += __shfl_xor(a7, 32, 64);
    // epilogue: lane sub holds features sub*8 .. sub*8+7 (all quarters identical)
    float dc = dinv[c], d2 = dc * dc;
    uint4 sb = *(const uint4*)&xw32[(size_t)c * 64 + sub * 4];
    float4 cb0 = *(const float4*)&conv_bias[sub * 8];
    float4 cb1 = *(const float4*)&conv_bias[sub * 8 + 4];
    float4 lw0 = *(const float4*)&lin_w[sub * 8];
    float4 lw1 = *(const float4*)&lin_w[sub * 8 + 4];
    float h0 = fmaxf(dc * a0 + d2 * bflo(sb.x) + cb0.x, 0.f);
    float h1 = fmaxf(dc * a1 + d2 * bfhi(sb.x) + cb0.y, 0.f);
    float h2 = fmaxf(dc * a2 + d2 * bflo(sb.y) + cb0.z, 0.f);
    float h3 = fmaxf(dc * a3 + d2 * bfhi(sb.y) + cb0.w, 0.f);
    float h4 = fmaxf(dc * a4 + d2 * bflo(sb.z) + cb1.x, 0.f);
    float h5 = fmaxf(dc * a5 + d2 * bfhi(sb.z) + cb1.y, 0.f);
    float h6 = fmaxf(dc * a6 + d2 * bflo(sb.w) + cb1.z, 0.f);
    float h7 = fmaxf(dc * a7 + d2 * bfhi(sb.w) + cb1.w, 0.f);
    float part = (h0 * lw0.x + h1 * lw0.y + h2 * lw0.z + h3 * lw0.w)
               + (h4 * lw1.x + h5 * lw1.y + h6 * lw1.z + h7 * lw1.w);
    part = (q == 0) ? part : 0.f;
    part = wave_reduce(part);
    if (lane == 0) out[c] = part + lin_b[0];
}

// ---------------- launch ----------------

extern "C" void kernel_launch(void* const* d_in, const int* in_sizes, int n_in,
                              void* d_out, int out_size, void* d_ws, size_t ws_size,
                              hipStream_t stream) {
    const float* x         = (const float*)d_in[0];
    const int*   ei        = (const int*)  d_in[1];
    const float* W         = (const float*)d_in[2];
    const float* p         = (const float*)d_in[3];
    const float* w_ih      = (const float*)d_in[4];
    const float* w_hh      = (const float*)d_in[5];
    const float* b_ih      = (const float*)d_in[6];
    const float* b_hh      = (const float*)d_in[7];
    const float* conv_bias = (const float*)d_in[8];
    const float* lin_w     = (const float*)d_in[9];
    const float* lin_b     = (const float*)d_in[10];
    float* out = (float*)d_out;

    u32*   w  = (u32*)d_ws;
    float* wf = (float*)d_ws;

    // ws layout (word offsets), ~41.6 MB. G (98304 w) overlays PAIRS (dead before
    // k_part). hist16/state/gcur contiguous -> ONE memset.
    const size_t SCORES_W = 0;          // 100000
    const size_t DINV_W   = 100096;     // 100000
    const size_t OFFS_W   = 200192;     // 100001
    const size_t HIST16_W = 300288;     // 65536
    const size_t STATE_W  = 365824;     // 8
    const size_t GCUR_W   = 365832;     // 196 (memset covers hist16..gcur)
    const size_t CAND_W   = 366080;     // 2048
    const size_t TOPI_W   = 368128;     // 128
    const size_t GATE_W   = 368256;     // 128
    const size_t WNEW_W   = 368384;     // 16384
    const size_t BFRAG_W  = 384768;     // 8192
    const size_t PAIRS_W  = 392960;     // 196 * 10240 = 2007040
    const size_t EBUF_W   = 2400000;    // 1600000
    const size_t XW_W     = 4000000;    // bf16 xw: 6400000 words

    float* scores  = wf + SCORES_W;
    float* dinv    = wf + DINV_W;
    u32*   offs    = w  + OFFS_W;
    u32*   hist16  = w  + HIST16_W;
    u32*   state   = w  + STATE_W;
    u32*   gcur    = w  + GCUR_W;
    u32*   cand    = w  + CAND_W;
    u32*   top_idx = w  + TOPI_W;
    float* gate    = wf + GATE_W;
    float* Wnew    = wf + WNEW_W;
    u16*   Bfrag   = (u16*)(w + BFRAG_W);
    u32*   pairs   = w  + PAIRS_W;
    float* G       = wf + PAIRS_W;      // overlay (dead before k_part)
    u32*   ebuf    = w  + EBUF_W;
    u16*   xwh     = (u16*)(w + XW_W);
    u32*   xw32    = w + XW_W;

    hipMemsetAsync(hist16, 0, (65536 + 8 + NBUCK) * sizeof(u32), stream);

    // --- top-k + GRU -> W_new (bf16 fragment-packed)
    k_scores<<<25000, 256, 0, stream>>>(x, p, scores, hist16);
    k_scan16<<<1, 1024, 0, stream>>>(hist16, state);
    k_collect16<<<392, 256, 0, stream>>>(scores, state, cand);
    k_assemble16<<<1, 256, 0, stream>>>(scores, p, state, cand, top_idx, gate);
    k_ggemm<<<dim3(4, 12), 256, 0, stream>>>(x, W, w_ih, w_hh, top_idx, gate, G);
    k_gate<<<64, 256, 0, stream>>>(G, W, b_ih, b_hh, Wnew, Bfrag);

    // --- xw = x @ W_new (bf16 MFMA)
    k_gemm<<<1563, 256, 0, stream>>>(x, Bfrag, xwh);

    // --- CSR build (fixed-capacity radix)
    k_part<<<(N_EDGES + PB_EDGES - 1) / PB_EDGES, 256, 0, stream>>>(ei, gcur, pairs);
    k_csr<<<NBUCK, 256, 0, stream>>>(pairs, gcur, offs, dinv, ebuf);

    // --- gather + fused head
    k_gather<<<25000, 256, 0, stream>>>(xw32, offs, ebuf, dinv, conv_bias, lin_w,
                                        lin_b, out);
}

// Round 10
// 326.297 us; speedup vs baseline: 1.9887x; 1.0133x over previous
//
#include <hip/hip_runtime.h>
#include <math.h>

#define N_NODES 100000
#define N_EDGES 1600000
#define F 128

// CSR radix: buckets of 512 destination nodes, fixed-capacity segments
#define BSH 9
#define NBUCK 196          // ceil(100000 / 512)
#define BCAP 10240         // per-bucket capacity (mean 8163, +22 sigma)
#define PB_EDGES 4096      // edges per k_part block

typedef unsigned int u32;
typedef unsigned short u16;
typedef __attribute__((ext_vector_type(8))) short short8;
typedef __attribute__((ext_vector_type(4))) float floatx4;

// ---------------- helpers ----------------

__device__ __forceinline__ u32 key_of(float s) {
    u32 u = __float_as_uint(s);
    return (u & 0x80000000u) ? ~u : (u | 0x80000000u);   // larger float -> larger key
}

__device__ __forceinline__ float wave_reduce(float v) {
    #pragma unroll
    for (int off = 32; off > 0; off >>= 1) v += __shfl_down(v, off, 64);
    return v;
}

__device__ __forceinline__ u16 f2bf(float f) {   // round-to-nearest-even
    u32 u = __float_as_uint(f);
    u += 0x7fffu + ((u >> 16) & 1u);
    return (u16)(u >> 16);
}

__device__ __forceinline__ float bflo(u32 b) { return __uint_as_float(b << 16); }
__device__ __forceinline__ float bfhi(u32 b) { return __uint_as_float(b & 0xffff0000u); }

// ---------------- 1. scores[i] = x[i] . p  (+ fused 16-bit key histogram) ----------

__global__ void k_scores(const float* __restrict__ x, const float* __restrict__ p,
                         float* __restrict__ scores, u32* __restrict__ hist16) {
    int node = blockIdx.x * 4 + (threadIdx.x >> 6);
    int lane = threadIdx.x & 63;
    if (node >= N_NODES) return;
    float2 xv = *(const float2*)&x[(size_t)node * F + lane * 2];
    float2 pv = *(const float2*)&p[lane * 2];
    float d = xv.x * pv.x + xv.y * pv.y;
    d = wave_reduce(d);
    if (lane == 0) {
        scores[node] = d;
        atomicAdd(&hist16[key_of(d) >> 16], 1u);
    }
}

// ---------------- 2. top-128 select ----------------

__global__ __launch_bounds__(1024) void k_scan16(const u32* __restrict__ hist16,
                                                 u32* __restrict__ state) {
    __shared__ u32 a[1024];
    int t = threadIdx.x;
    const uint4* h4 = (const uint4*)hist16;
    u32 local = 0;
    #pragma unroll
    for (int i = 0; i < 16; i++) {
        uint4 v = h4[t * 16 + i];
        local += v.x + v.y + v.z + v.w;
    }
    a[t] = local;
    __syncthreads();
    for (int off = 1; off < 1024; off <<= 1) {
        u32 add = (t + off < 1024) ? a[t + off] : 0u;
        __syncthreads();
        a[t] += add;
        __syncthreads();
    }
    u32 S_above = (t == 1023) ? 0u : a[t + 1];
    if (S_above < 128u && a[t] >= 128u) {     // threshold bucket is in my chunk
        u32 cum = S_above;
        for (int v = t * 64 + 63; v >= t * 64; v--) {
            cum += hist16[v];
            if (cum >= 128u) { state[0] = (u32)v; break; }
        }
    }
}

__global__ void k_collect16(const float* __restrict__ scores, u32* __restrict__ state,
                            u32* __restrict__ cand) {
    u32 T = state[0] << 16;
    int i = blockIdx.x * blockDim.x + threadIdx.x;
    if (i < N_NODES) {
        if (key_of(scores[i]) >= T) {
            u32 pos = atomicAdd(&state[2], 1u);
            if (pos < 2048u) cand[pos] = (u32)i;
        }
    }
}

__global__ void k_assemble16(const float* __restrict__ scores, const float* __restrict__ p,
                             const u32* __restrict__ state, const u32* __restrict__ cand,
                             u32* __restrict__ top_idx, float* __restrict__ gate) {
    __shared__ u32 ci[2048];
    __shared__ float csc[2048];
    __shared__ float s_inv;
    int t = threadIdx.x;   // 256 threads
    if (t < 64) {
        float2 pv = *(const float2*)&p[t * 2];
        float d = pv.x * pv.x + pv.y * pv.y;
        d = wave_reduce(d);
        if (t == 0) s_inv = rsqrtf(d);
    }
    u32 nc = state[2]; if (nc > 2048u) nc = 2048u;
    for (u32 i = t; i < nc; i += 256) { u32 ix = cand[i]; ci[i] = ix; csc[i] = scores[ix]; }
    __syncthreads();
    for (u32 i = t; i < nc; i += 256) {
        u32 myk = key_of(csc[i]);
        u32 myi = ci[i];
        int rank = 0;
        for (u32 j = 0; j < nc; j++) {
            u32 ok = key_of(csc[j]);
            rank += (int)((ok > myk) || (ok == myk && ci[j] < myi));
        }
        if (rank < 128) {   // exact jax semantics: value desc, index asc on ties
            top_idx[rank] = myi;
            gate[rank] = tanhf(csc[i] * s_inv);
        }
    }
}

// ---------------- 3a. GRU GEMMs: g[128][768] = [x_tilde | W] . [w_ih | w_hh]^T -----

__global__ __launch_bounds__(256) void k_ggemm(const float* __restrict__ x,
                                               const float* __restrict__ W,
                                               const float* __restrict__ w_ih,
                                               const float* __restrict__ w_hh,
                                               const u32* __restrict__ top_idx,
                                               const float* __restrict__ gate,
                                               float* __restrict__ G) {
    __shared__ float As[32][128];
    __shared__ float Bs[64][131];
    int t = threadIdx.x;
    int k0 = blockIdx.x * 32;
    int by = blockIdx.y;                // 0..11; <6 -> gi (w_ih, x_tilde), else gh
    int j0 = by * 64;
    bool is_gi = (by < 6);
    #pragma unroll
    for (int i = 0; i < 4; i++) {
        int l = t + i * 256;
        int row = l >> 5, c4 = l & 31;
        float4 v;
        if (is_gi) {
            u32 idx = top_idx[k0 + row];
            float gt = gate[k0 + row];
            v = *(const float4*)&x[(size_t)idx * F + c4 * 4];
            v.x *= gt; v.y *= gt; v.z *= gt; v.w *= gt;
        } else {
            v = *(const float4*)&W[(k0 + row) * F + c4 * 4];
        }
        *(float4*)&As[row][c4 * 4] = v;
    }
    const float* mat = is_gi ? w_ih : w_hh;
    int jbase = is_gi ? j0 : (j0 - 384);
    #pragma unroll
    for (int i = 0; i < 8; i++) {
        int l = t + i * 256;
        int row = l >> 5, c4 = l & 31;
        float4 v = *(const float4*)&mat[(jbase + row) * F + c4 * 4];
        Bs[row][c4 * 4 + 0] = v.x; Bs[row][c4 * 4 + 1] = v.y;
        Bs[row][c4 * 4 + 2] = v.z; Bs[row][c4 * 4 + 3] = v.w;
    }
    __syncthreads();
    int ty = t >> 5, tx = t & 31;
    float acc[4][2] = {};
    #pragma unroll 4
    for (int f = 0; f < 128; f++) {
        float b0 = Bs[tx * 2][f], b1 = Bs[tx * 2 + 1][f];
        #pragma unroll
        for (int i = 0; i < 4; i++) {
            float a = As[ty * 4 + i][f];
            acc[i][0] += a * b0;
            acc[i][1] += a * b1;
        }
    }
    #pragma unroll
    for (int i = 0; i < 4; i++) {
        int k = k0 + ty * 4 + i;
        G[(size_t)k * 768 + j0 + tx * 2 + 0] = acc[i][0];
        G[(size_t)k * 768 + j0 + tx * 2 + 1] = acc[i][1];
    }
}

// ---------------- 3b. pointwise GRU gates -> Wnew + fragment-ordered bf16 B --------

__global__ void k_gate(const float* __restrict__ G, const float* __restrict__ W,
                       const float* __restrict__ b_ih, const float* __restrict__ b_hh,
                       float* __restrict__ Wnew, u16* __restrict__ Bfrag) {
    int idx = blockIdx.x * blockDim.x + threadIdx.x;   // 16384
    int k = idx >> 7, h = idx & 127;
    const float* gk = &G[(size_t)k * 768];
    float gir = gk[h]       + b_ih[h];
    float giz = gk[128 + h] + b_ih[128 + h];
    float gin = gk[256 + h] + b_ih[256 + h];
    float ghr = gk[384 + h] + b_hh[h];
    float ghz = gk[512 + h] + b_hh[128 + h];
    float ghn = gk[640 + h] + b_hh[256 + h];
    float wv  = W[k * F + h];
    float rg = 1.0f / (1.0f + expf(-(gir + ghr)));
    float z  = 1.0f / (1.0f + expf(-(giz + ghz)));
    float n  = tanhf(gin + rg * ghn);
    float val = (1.0f - z) * n + z * wv;
    Wnew[k * F + h] = val;
    int nb = h >> 4, kc = k >> 5, q = (k >> 3) & 3, m = h & 15, jj = k & 7;
    Bfrag[(((nb * 4 + kc) * 64) + q * 16 + m) * 8 + jj] = f2bf(val);
}

// ---------------- 4. CSR build: fixed-capacity radix scatter -----------------------

__global__ void k_part(const int* __restrict__ ei, u32* __restrict__ gcur,
                       u32* __restrict__ pairs) {
    __shared__ u32 lh[NBUCK];     // local histogram, then local cursor
    __shared__ u32 lbase[NBUCK];  // reserved base within bucket segment
    int t = threadIdx.x;
    int e0 = blockIdx.x * PB_EDGES;
    int e1 = e0 + PB_EDGES; if (e1 > N_EDGES) e1 = N_EDGES;
    for (int i = t; i < NBUCK; i += 256) lh[i] = 0u;
    __syncthreads();
    for (int e = e0 + t; e < e1; e += 256)
        atomicAdd(&lh[((u32)ei[N_EDGES + e]) >> BSH], 1u);
    __syncthreads();
    for (int b = t; b < NBUCK; b += 256) {
        u32 c = lh[b];
        lbase[b] = c ? atomicAdd(&gcur[b], c) : 0u;
        lh[b] = 0u;
    }
    __syncthreads();
    for (int e = e0 + t; e < e1; e += 256) {
        u32 d = (u32)ei[N_EDGES + e];
        u32 b = d >> BSH;
        u32 pos = lbase[b] + atomicAdd(&lh[b], 1u);
        pairs[(size_t)b * BCAP + pos] = ((d & 511u) << 17) | (u32)ei[e];
    }
}

__global__ __launch_bounds__(256) void k_csr(const u32* __restrict__ pairs,
                                             const u32* __restrict__ gcur,
                                             u32* __restrict__ offs,
                                             float* __restrict__ dinv,
                                             u32* __restrict__ ebuf) {
    __shared__ u32 h[512];
    __shared__ u32 sc[512];
    __shared__ u32 ps[256];
    int b = blockIdx.x, t = threadIdx.x;
    u32 pv = (t < NBUCK) ? gcur[t] : 0u;
    ps[t] = pv;
    __syncthreads();
    for (int off = 1; off < 256; off <<= 1) {
        u32 add = (t >= off) ? ps[t - off] : 0u;
        __syncthreads();
        ps[t] += add;
        __syncthreads();
    }
    u32 base = ps[b] - gcur[b];
    u32 cnt  = gcur[b];
    const u32* seg = pairs + (size_t)b * BCAP;
    u32 lo = (u32)b << BSH;
    for (int i = t; i < 512; i += 256) h[i] = 0u;
    __syncthreads();
    for (u32 i = t; i < cnt; i += 256)
        atomicAdd(&h[seg[i] >> 17], 1u);
    __syncthreads();
    for (int i = t; i < 512; i += 256) sc[i] = h[i];
    __syncthreads();
    for (int off = 1; off < 512; off <<= 1) {
        int i0 = t, i1 = t + 256;
        u32 v0 = (i0 >= off) ? sc[i0 - off] : 0u;
        u32 v1 = (i1 >= off) ? sc[i1 - off] : 0u;
        __syncthreads();
        sc[i0] += v0; sc[i1] += v1;
        __syncthreads();
    }
    int nn = N_NODES - (int)lo; if (nn > 512) nn = 512;
    for (int i = t; i < nn; i += 256) {
        u32 c = h[i];
        offs[lo + i] = base + (sc[i] - c);
        dinv[lo + i] = rsqrtf((float)c + 1.0f);
    }
    for (int i = t; i < 512; i += 256) sc[i] -= h[i];
    __syncthreads();
    for (u32 i = t; i < cnt; i += 256) {
        u32 pr = seg[i];
        u32 pos = base + atomicAdd(&sc[pr >> 17], 1u);
        ebuf[pos] = pr & 0x1ffffu;
    }
    if (b == 0 && t == 0) offs[N_NODES] = N_EDGES;
}

// ---------------- 5. yw = dinv * (x @ W_new) : bf16 MFMA, direct-global B, LDS-
// transposed coalesced epilogue. LDS 17 KB -> high occupancy.

__global__ __launch_bounds__(256) void k_gemm(const float* __restrict__ x,
                                              const u16* __restrict__ Bfrag,
                                              const float* __restrict__ dinv,
                                              u16* __restrict__ yw) {
    __shared__ __align__(16) u16 As[8448];    // frag stage (8192) / epilogue 64x132
    int t = threadIdx.x;
    int r0 = blockIdx.x * 64;
    // stage A: 64 rows x 128 f, fp32 -> bf16 fragment order
    #pragma unroll
    for (int i = 0; i < 8; i++) {
        int l = t + i * 256;              // 2048 float4s
        int row = l >> 5, c4 = l & 31;
        int f0 = c4 * 4;
        float4 v = {0.f, 0.f, 0.f, 0.f};
        if (r0 + row < N_NODES) v = *(const float4*)&x[(size_t)(r0 + row) * F + f0];
        int widx = (((row >> 4) * 4 + (f0 >> 5)) * 64 + ((f0 >> 3) & 3) * 16 + (row & 15)) * 8
                   + (f0 & 7);
        ushort4 s4;
        s4.x = f2bf(v.x); s4.y = f2bf(v.y); s4.z = f2bf(v.z); s4.w = f2bf(v.w);
        *(ushort4*)&As[widx] = s4;
    }
    __syncthreads();

    int wv = t >> 6, lane = t & 63;
    int q = lane >> 4, m = lane & 15;
    floatx4 acc[8] = {};
    #pragma unroll
    for (int kc = 0; kc < 4; kc++) {
        short8 a = *(const short8*)&As[((wv * 4 + kc) * 64 + lane) * 8];
        #pragma unroll
        for (int nb = 0; nb < 8; nb++) {
            short8 bfr = *(const short8*)&Bfrag[((nb * 4 + kc) * 64 + lane) * 8];
            acc[nb] = __builtin_amdgcn_mfma_f32_16x16x32_bf16(a, bfr, acc[nb], 0, 0, 0);
        }
    }
    __syncthreads();   // done reading A-frags; reuse As as epilogue buffer

    float d[4];
    #pragma unroll
    for (int reg = 0; reg < 4; reg++) {
        int gr = r0 + wv * 16 + q * 4 + reg;
        d[reg] = (gr < N_NODES) ? dinv[gr] : 0.f;
    }
    #pragma unroll
    for (int nb = 0; nb < 8; nb++) {
        #pragma unroll
        for (int reg = 0; reg < 4; reg++) {
            int row = wv * 16 + q * 4 + reg;
            As[row * 132 + nb * 16 + m] = f2bf(acc[nb][reg] * d[reg]);
        }
    }
    __syncthreads();
    // coalesced store: thread t -> row t>>2, 32-col segment (t&3)*32 (64 B)
    {
        int row = t >> 2, segi = t & 3;
        int gr = r0 + row;
        if (gr < N_NODES) {
            const uint2* src = (const uint2*)&As[row * 132 + segi * 32];
            uint2* dst = (uint2*)&yw[(size_t)gr * F + segi * 32];
            #pragma unroll
            for (int i = 0; i < 8; i++) dst[i] = src[i];
        }
    }
}

// ---------------- 6. gather-aggregate + fused head (pre-scaled yw rows) -----------
// One wave per node; quarter-wave per edge (uint4 = 8 bf16/lane). Pure adds.

#define EDGE_GROUP(J) {                                                      \
    u32 r = ebuf[(J) + q];                                                   \
    uint4 bb = *(const uint4*)&yw32[(size_t)r * 64 + sub * 4];               \
    a0 += bflo(bb.x); a1 += bfhi(bb.x);                                      \
    a2 += bflo(bb.y); a3 += bfhi(bb.y);                                      \
    a4 += bflo(bb.z); a5 += bfhi(bb.z);                                      \
    a6 += bflo(bb.w); a7 += bfhi(bb.w); }

__global__ void k_gather(const u32* __restrict__ yw32, const u32* __restrict__ offs,
                         const u32* __restrict__ ebuf, const float* __restrict__ dinv,
                         const float* __restrict__ conv_bias, const float* __restrict__ lin_w,
                         const float* __restrict__ lin_b, float* __restrict__ out) {
    int c = blockIdx.x * 4 + (threadIdx.x >> 6);
    if (c >= N_NODES) return;
    int lane = threadIdx.x & 63;
    int q = lane >> 4, sub = lane & 15;
    u32 jbeg = offs[c], jend = offs[c + 1];
    float a0 = 0.f, a1 = 0.f, a2 = 0.f, a3 = 0.f;
    float a4 = 0.f, a5 = 0.f, a6 = 0.f, a7 = 0.f;
    u32 j = jbeg;
    for (; j + 16 <= jend; j += 16) {   // 16 edges (4 quad-groups) in flight
        EDGE_GROUP(j) EDGE_GROUP(j + 4) EDGE_GROUP(j + 8) EDGE_GROUP(j + 12)
    }
    for (; j + 4 <= jend; j += 4) EDGE_GROUP(j)
    u32 rem = jend - j;
    if (rem) {                           // 1..3 leftover edges
        u32 idx = ((u32)q < rem) ? (j + q) : (jend - 1);
        u32 r = ebuf[idx];
        float mk = ((u32)q < rem) ? 1.f : 0.f;
        uint4 bb = *(const uint4*)&yw32[(size_t)r * 64 + sub * 4];
        a0 += mk * bflo(bb.x); a1 += mk * bfhi(bb.x);
        a2 += mk * bflo(bb.y); a3 += mk * bfhi(bb.y);
        a4 += mk * bflo(bb.z); a5 += mk * bfhi(bb.z);
        a6 += mk * bflo(bb.w); a7 += mk * bfhi(bb.w);
    }
    // combine quarters: butterfly over lane^16, lane^32
    a0 += __shfl_xor(a0, 16, 64); a0 += __shfl_xor(a0, 32, 64);
    a1 += __shfl_xor(a1, 16, 64); a1 += __shfl_xor(a1, 32, 64);
    a2 += __shfl_xor(a2, 16, 64); a2 += __shfl_xor(a2, 32, 64);
    a3 += __shfl_xor(a3, 16, 64); a3 += __shfl_xor(a3, 32, 64);
    a4 += __shfl_xor(a4, 16, 64); a4 += __shfl_xor(a4, 32, 64);
    a5 += __shfl_xor(a5, 16, 64); a5 += __shfl_xor(a5, 32, 64);
    a6 += __shfl_xor(a6, 16, 64); a6 += __shfl_xor(a6, 32, 64);
    a7 += __shfl_xor(a7, 16, 64); a7 += __shfl_xor(a7, 32, 64);
    // epilogue: agg = dc*(sum + yw_c) + bias; relu; dot with lin_w
    float dc = dinv[c];
    uint4 sb = *(const uint4*)&yw32[(size_t)c * 64 + sub * 4];
    float4 cb0 = *(const float4*)&conv_bias[sub * 8];
    float4 cb1 = *(const float4*)&conv_bias[sub * 8 + 4];
    float4 lw0 = *(const float4*)&lin_w[sub * 8];
    float4 lw1 = *(const float4*)&lin_w[sub * 8 + 4];
    float h0 = fmaxf(dc * (a0 + bflo(sb.x)) + cb0.x, 0.f);
    float h1 = fmaxf(dc * (a1 + bfhi(sb.x)) + cb0.y, 0.f);
    float h2 = fmaxf(dc * (a2 + bflo(sb.y)) + cb0.z, 0.f);
    float h3 = fmaxf(dc * (a3 + bfhi(sb.y)) + cb0.w, 0.f);
    float h4 = fmaxf(dc * (a4 + bflo(sb.z)) + cb1.x, 0.f);
    float h5 = fmaxf(dc * (a5 + bfhi(sb.z)) + cb1.y, 0.f);
    float h6 = fmaxf(dc * (a6 + bflo(sb.w)) + cb1.z, 0.f);
    float h7 = fmaxf(dc * (a7 + bfhi(sb.w)) + cb1.w, 0.f);
    float part = (h0 * lw0.x + h1 * lw0.y + h2 * lw0.z + h3 * lw0.w)
               + (h4 * lw1.x + h5 * lw1.y + h6 * lw1.z + h7 * lw1.w);
    part = (q == 0) ? part : 0.f;
    part = wave_reduce(part);
    if (lane == 0) out[c] = part + lin_b[0];
}

// ---------------- launch ----------------

extern "C" void kernel_launch(void* const* d_in, const int* in_sizes, int n_in,
                              void* d_out, int out_size, void* d_ws, size_t ws_size,
                              hipStream_t stream) {
    const float* x         = (const float*)d_in[0];
    const int*   ei        = (const int*)  d_in[1];
    const float* W         = (const float*)d_in[2];
    const float* p         = (const float*)d_in[3];
    const float* w_ih      = (const float*)d_in[4];
    const float* w_hh      = (const float*)d_in[5];
    const float* b_ih      = (const float*)d_in[6];
    const float* b_hh      = (const float*)d_in[7];
    const float* conv_bias = (const float*)d_in[8];
    const float* lin_w     = (const float*)d_in[9];
    const float* lin_b     = (const float*)d_in[10];
    float* out = (float*)d_out;

    u32*   w  = (u32*)d_ws;
    float* wf = (float*)d_ws;

    // ws layout (word offsets), ~41.6 MB. G overlays PAIRS (dead before k_part).
    const size_t SCORES_W = 0;          // 100000
    const size_t DINV_W   = 100096;     // 100000
    const size_t OFFS_W   = 200192;     // 100001
    const size_t HIST16_W = 300288;     // 65536
    const size_t STATE_W  = 365824;     // 8
    const size_t GCUR_W   = 365832;     // 196 (memset covers hist16..gcur)
    const size_t CAND_W   = 366080;     // 2048
    const size_t TOPI_W   = 368128;     // 128
    const size_t GATE_W   = 368256;     // 128
    const size_t WNEW_W   = 368384;     // 16384
    const size_t BFRAG_W  = 384768;     // 8192
    const size_t PAIRS_W  = 392960;     // 196 * 10240 = 2007040
    const size_t EBUF_W   = 2400000;    // 1600000
    const size_t YW_W     = 4000000;    // bf16 yw: 6400000 words

    float* scores  = wf + SCORES_W;
    float* dinv    = wf + DINV_W;
    u32*   offs    = w  + OFFS_W;
    u32*   hist16  = w  + HIST16_W;
    u32*   state   = w  + STATE_W;
    u32*   gcur    = w  + GCUR_W;
    u32*   cand    = w  + CAND_W;
    u32*   top_idx = w  + TOPI_W;
    float* gate    = wf + GATE_W;
    float* Wnew    = wf + WNEW_W;
    u16*   Bfrag   = (u16*)(w + BFRAG_W);
    u32*   pairs   = w  + PAIRS_W;
    float* G       = wf + PAIRS_W;      // overlay (dead before k_part)
    u32*   ebuf    = w  + EBUF_W;
    u16*   yw      = (u16*)(w + YW_W);
    u32*   yw32    = w + YW_W;

    hipMemsetAsync(hist16, 0, (65536 + 8 + NBUCK) * sizeof(u32), stream);

    // --- top-k (proven 4-kernel chain)
    k_scores<<<25000, 256, 0, stream>>>(x, p, scores, hist16);
    k_scan16<<<1, 1024, 0, stream>>>(hist16, state);
    k_collect16<<<392, 256, 0, stream>>>(scores, state, cand);
    k_assemble16<<<1, 256, 0, stream>>>(scores, p, state, cand, top_idx, gate);

    // --- GRU -> W_new (bf16 fragment-packed)
    k_ggemm<<<dim3(4, 12), 256, 0, stream>>>(x, W, w_ih, w_hh, top_idx, gate, G);
    k_gate<<<64, 256, 0, stream>>>(G, W, b_ih, b_hh, Wnew, Bfrag);

    // --- CSR build (fixed-capacity radix) -> offs, dinv, ebuf
    k_part<<<(N_EDGES + PB_EDGES - 1) / PB_EDGES, 256, 0, stream>>>(ei, gcur, pairs);
    k_csr<<<NBUCK, 256, 0, stream>>>(pairs, gcur, offs, dinv, ebuf);

    // --- yw = dinv * (x @ W_new)  (bf16 MFMA)
    k_gemm<<<1563, 256, 0, stream>>>(x, Bfrag, dinv, yw);

    // --- gather + fused head
    k_gather<<<25000, 256, 0, stream>>>(yw32, offs, ebuf, dinv, conv_bias, lin_w,
                                        lin_b, out);
}